// Round 6
// baseline (438.710 us; speedup 1.0000x reference)
//
#include <hip/hip_runtime.h>
#include <math.h>

// PhysioGAT pipeline on MI355X.
// Layer-1 trick: h1 = x@W1 is linear in 3-dim x, so the alpha-weighted
// neighbor sum is (sum alpha*x[src]) @ W1 — h1 is never materialized.
// Output: concat(heat[64,3], dehyd[64,2]) = 320 f32.

#define N_NODES 30000
#define N_GRAPHS 64

// ---------------- Layer-1 attention logits: a_s1/a_d1[n,8] -----------------
// a_s[n,h] = x[n,:] . P_s[:,h],  P_s[d,h] = sum_c W1[d,h*64+c]*att_src[h,c]
__global__ __launch_bounds__(256) void k_att1(
    const float* __restrict__ x, const float* __restrict__ W1,
    const float* __restrict__ asw, const float* __restrict__ adw,
    float* __restrict__ a_s, float* __restrict__ a_d, int n)
{
    __shared__ float Ps[24], Pd[24];          // idx = d*8 + h
    int t = threadIdx.x;
    if (t < 48) {
        int which = t / 24;                   // 0 -> Ps, 1 -> Pd
        int idx = t - which * 24;
        int d = idx >> 3, h = idx & 7;
        const float* av = (which ? adw : asw) + h * 64;
        const float* wr = W1 + d * 512 + h * 64;
        float s = 0.f;
        #pragma unroll 8
        for (int c = 0; c < 64; ++c) s = fmaf(wr[c], av[c], s);
        (which ? Pd : Ps)[idx] = s;
    }
    __syncthreads();
    int node = blockIdx.x * 256 + t;
    if (node >= n) return;
    float x0 = x[node * 3 + 0];
    float x1v = x[node * 3 + 1];
    float x2v = x[node * 3 + 2];
    #pragma unroll
    for (int h = 0; h < 8; ++h) {
        a_s[node * 8 + h] = fmaf(x0, Ps[h], fmaf(x1v, Ps[8 + h], x2v * Ps[16 + h]));
        a_d[node * 8 + h] = fmaf(x0, Pd[h], fmaf(x1v, Pd[8 + h], x2v * Pd[16 + h]));
    }
}

// ---------------- CSR build ------------------------------------------------
__global__ void k_deg(const int* __restrict__ ei, int* __restrict__ deg,
                      int E0, int n)
{
    int e = blockIdx.x * blockDim.x + threadIdx.x;
    int Et = E0 + n;
    if (e >= Et) return;
    int dst = (e < E0) ? ei[E0 + e] : (e - E0);
    atomicAdd(&deg[dst], 1);
}

__global__ __launch_bounds__(1024) void k_scan(
    const int* __restrict__ deg, int* __restrict__ rowstart,
    int* __restrict__ cursor, int n)
{
    __shared__ int wsum[16];
    __shared__ int woff[17];
    __shared__ int carry_s;
    int tid = threadIdx.x, lane = tid & 63, wid = tid >> 6;
    if (tid == 0) carry_s = 0;
    __syncthreads();
    int nchunks = (n + 1023) >> 10;
    for (int c = 0; c < nchunks; ++c) {
        int i = (c << 10) + tid;
        int v = (i < n) ? deg[i] : 0;
        int s = v;                                   // wave inclusive scan
        #pragma unroll
        for (int off = 1; off < 64; off <<= 1) {
            int t = __shfl_up(s, off);
            if (lane >= off) s += t;
        }
        if (lane == 63) wsum[wid] = s;
        __syncthreads();
        if (wid == 0) {                              // scan the 16 wave sums
            int ws = (lane < 16) ? wsum[lane] : 0;
            #pragma unroll
            for (int off = 1; off < 16; off <<= 1) {
                int t = __shfl_up(ws, off);
                if (lane >= off) ws += t;
            }
            if (lane < 16) woff[lane + 1] = ws;
            if (lane == 0) woff[0] = 0;
        }
        __syncthreads();
        int excl = carry_s + woff[wid] + s - v;
        if (i < n) { rowstart[i] = excl; cursor[i] = excl; }
        __syncthreads();
        if (tid == 0) carry_s += woff[16];
        __syncthreads();
    }
    if (tid == 0) rowstart[n] = carry_s;
}

__global__ void k_fill(const int* __restrict__ ei, int* __restrict__ cursor,
                       int* __restrict__ csr, int E0, int n)
{
    int e = blockIdx.x * blockDim.x + threadIdx.x;
    int Et = E0 + n;
    if (e >= Et) return;
    int src, dst;
    if (e < E0) { src = ei[e]; dst = ei[E0 + e]; }
    else        { src = e - E0; dst = e - E0; }
    int pos = atomicAdd(&cursor[dst], 1);
    csr[pos] = src;
}

// ---------------- GAT layer 1: online softmax over S = sum alpha*x[src] ----
// wave per node; hd = lane>>3 (8 heads), slot = lane&7 strides edges.
// Epilogue: x1[node, hd*64 + c] = relu(S . W1[:, col] / ssum + bias).
__global__ __launch_bounds__(256) void k_gat1(
    const float* __restrict__ x, const float* __restrict__ W1,
    const float* __restrict__ a_s, const float* __restrict__ a_d,
    const int* __restrict__ rowstart, const int* __restrict__ csr,
    const float* __restrict__ bias, float* __restrict__ x1, int n)
{
    int lane = threadIdx.x & 63;
    int node = blockIdx.x * 4 + (threadIdx.x >> 6);
    if (node >= n) return;
    int rs = rowstart[node], re = rowstart[node + 1];
    int hd = lane >> 3;
    int slot = lane & 7;
    float adn = a_d[node * 8 + hd];

    float m = -1e30f, ssum = 0.f, S0 = 0.f, S1 = 0.f, S2 = 0.f;
    for (int i = rs + slot; i < re; i += 8) {
        int src = csr[i];
        float e = a_s[src * 8 + hd] + adn;
        e = (e >= 0.f) ? e : 0.2f * e;
        float x0 = x[src * 3 + 0];
        float x1v = x[src * 3 + 1];
        float x2v = x[src * 3 + 2];
        float mn = fmaxf(m, e);
        float sc = __expf(m - mn);
        float wgt = __expf(e - mn);
        ssum = fmaf(ssum, sc, wgt);
        S0 = fmaf(S0, sc, wgt * x0);
        S1 = fmaf(S1, sc, wgt * x1v);
        S2 = fmaf(S2, sc, wgt * x2v);
        m = mn;
    }
    #pragma unroll
    for (int off = 1; off < 8; off <<= 1) {   // merge 8 slots of this head
        float mo = __shfl_xor(m, off);
        float so = __shfl_xor(ssum, off);
        float t0 = __shfl_xor(S0, off);
        float t1 = __shfl_xor(S1, off);
        float t2 = __shfl_xor(S2, off);
        float mn = fmaxf(m, mo);
        float scA = __expf(m - mn);
        float scB = __expf(mo - mn);
        ssum = ssum * scA + so * scB;
        S0 = S0 * scA + t0 * scB;
        S1 = S1 * scA + t1 * scB;
        S2 = S2 * scA + t2 * scB;
        m = mn;
    }
    float inv = 1.f / ssum;
    S0 *= inv; S1 *= inv; S2 *= inv;

    // epilogue: features j = lane*8 .. lane*8+7 (all in head hd)
    const float4* w0p = (const float4*)(W1 + lane * 8);
    const float4* w1p = (const float4*)(W1 + 512 + lane * 8);
    const float4* w2p = (const float4*)(W1 + 1024 + lane * 8);
    const float4* bp  = (const float4*)(bias + lane * 8);
    float4* xp = (float4*)(x1 + (size_t)node * 512 + lane * 8);
    #pragma unroll
    for (int q = 0; q < 2; ++q) {
        float4 w0 = w0p[q], w1 = w1p[q], w2 = w2p[q], b = bp[q];
        float4 o;
        o.x = fmaxf(fmaf(S0, w0.x, fmaf(S1, w1.x, fmaf(S2, w2.x, b.x))), 0.f);
        o.y = fmaxf(fmaf(S0, w0.y, fmaf(S1, w1.y, fmaf(S2, w2.y, b.y))), 0.f);
        o.z = fmaxf(fmaf(S0, w0.z, fmaf(S1, w1.z, fmaf(S2, w2.z, b.z))), 0.f);
        o.w = fmaxf(fmaf(S0, w0.w, fmaf(S1, w1.w, fmaf(S2, w2.w, b.w))), 0.f);
        xp[q] = o;
    }
}

// ---------------- Layer-2 GEMM + fused attention dots ----------------------
// h2[30000,128] = x1[30000,512] @ W2[512,128]; also a_s2/a_d2[n,4].
// BM=32 rows/block -> 938 blocks (occupancy fix; old 128-row tile gave only
// 235 blocks for 256 CUs = 9.6% occupancy). 256 threads: tr=tid>>5 (8 row
// groups x 4 rows), tc=tid&31 (cols tc*4..tc*4+3, all in head tc>>3).
#define BM2 32
__global__ __launch_bounds__(256) void k_gemm2(
    const float* __restrict__ x1, const float* __restrict__ W2,
    const float* __restrict__ asw, const float* __restrict__ adw,
    float* __restrict__ h2, float* __restrict__ a_s2, float* __restrict__ a_d2,
    int n)
{
    int tid = threadIdx.x;
    int tr = tid >> 5;                 // 0..7 row group
    int tc = tid & 31;                 // 0..31 col group (4 cols)
    int bm = blockIdx.x * BM2;

    float acc[4][4];
    #pragma unroll
    for (int r = 0; r < 4; ++r)
        #pragma unroll
        for (int c = 0; c < 4; ++c) acc[r][c] = 0.f;

    const float* arow[4];
    #pragma unroll
    for (int r = 0; r < 4; ++r) {
        int row = bm + tr * 4 + r;
        row = row < n ? row : (n - 1);           // clamp (writes guarded)
        arow[r] = x1 + (size_t)row * 512;
    }
    const float* bcol = W2 + tc * 4;

    for (int k = 0; k < 512; k += 4) {
        float a_[4][4];
        #pragma unroll
        for (int r = 0; r < 4; ++r) {
            float4 av = *(const float4*)(arow[r] + k);
            a_[r][0] = av.x; a_[r][1] = av.y; a_[r][2] = av.z; a_[r][3] = av.w;
        }
        float b_[4][4];
        #pragma unroll
        for (int kk = 0; kk < 4; ++kk) {
            float4 bv = *(const float4*)(bcol + (size_t)(k + kk) * 128);
            b_[kk][0] = bv.x; b_[kk][1] = bv.y; b_[kk][2] = bv.z; b_[kk][3] = bv.w;
        }
        #pragma unroll
        for (int kk = 0; kk < 4; ++kk)
            #pragma unroll
            for (int r = 0; r < 4; ++r)
                #pragma unroll
                for (int c = 0; c < 4; ++c)
                    acc[r][c] = fmaf(a_[r][kk], b_[kk][c], acc[r][c]);
    }

    // h2 writes
    #pragma unroll
    for (int r = 0; r < 4; ++r) {
        int row = bm + tr * 4 + r;
        if (row < n) {
            float4 o;
            o.x = acc[r][0]; o.y = acc[r][1]; o.z = acc[r][2]; o.w = acc[r][3];
            *(float4*)(h2 + (size_t)row * 128 + tc * 4) = o;
        }
    }

    // fused attention dots: head = tc>>3; reduce over 8 lanes (tc bits 0..2)
    float4 ws = *(const float4*)(asw + tc * 4);
    float4 wd = *(const float4*)(adw + tc * 4);
    float ps[4], pd[4];
    #pragma unroll
    for (int r = 0; r < 4; ++r) {
        ps[r] = acc[r][0] * ws.x + acc[r][1] * ws.y + acc[r][2] * ws.z + acc[r][3] * ws.w;
        pd[r] = acc[r][0] * wd.x + acc[r][1] * wd.y + acc[r][2] * wd.z + acc[r][3] * wd.w;
    }
    #pragma unroll
    for (int off = 1; off < 8; off <<= 1) {
        #pragma unroll
        for (int r = 0; r < 4; ++r) {
            ps[r] += __shfl_xor(ps[r], off);
            pd[r] += __shfl_xor(pd[r], off);
        }
    }
    if ((tc & 7) == 0) {
        int hd = tc >> 3;
        #pragma unroll
        for (int r = 0; r < 4; ++r) {
            int row = bm + tr * 4 + r;
            if (row < n) {
                a_s2[row * 4 + hd] = ps[r];
                a_d2[row * 4 + hd] = pd[r];
            }
        }
    }
}

// ---------------- GAT layer 2: single-pass online softmax + residual -------
// Lane owns features 2*lane, 2*lane+1 (head hd=lane>>4). All lanes iterate
// all edges; (m,ssum) duplicated within a head group -> no cross-lane reduce.
__global__ __launch_bounds__(256) void k_gat2(
    const float* __restrict__ h2, const float* __restrict__ a_s,
    const float* __restrict__ a_d, const int* __restrict__ rowstart,
    const int* __restrict__ csr, const float* __restrict__ bias,
    const float* __restrict__ x1, float* __restrict__ hres, int n)
{
    int lane = threadIdx.x & 63;
    int node = blockIdx.x * 4 + (threadIdx.x >> 6);
    if (node >= n) return;
    int rs = rowstart[node], re = rowstart[node + 1];
    int hd = lane >> 4;                       // head (0..3)
    float adn = a_d[node * 4 + hd];

    float m = -1e30f, ssum = 0.f, acc0 = 0.f, acc1 = 0.f;
    int src_next = (rs < re) ? csr[rs] : 0;
    for (int i = rs; i < re; ++i) {
        int src = src_next;
        if (i + 1 < re) src_next = csr[i + 1];
        float e = a_s[src * 4 + hd] + adn;
        e = (e >= 0.f) ? e : 0.2f * e;
        float2 hv = *(const float2*)(h2 + (size_t)src * 128 + lane * 2);
        float mn = fmaxf(m, e);
        float sc = __expf(m - mn);
        float wgt = __expf(e - mn);
        ssum = fmaf(ssum, sc, wgt);
        acc0 = fmaf(acc0, sc, wgt * hv.x);
        acc1 = fmaf(acc1, sc, wgt * hv.y);
        m = mn;
    }
    float inv = 1.f / ssum;
    float2 xv = *(const float2*)(x1 + (size_t)node * 512 + lane * 2);
    float2 o;
    o.x = xv.x + fmaxf(fmaf(acc0, inv, bias[lane * 2 + 0]), 0.f);
    o.y = xv.y + fmaxf(fmaf(acc1, inv, bias[lane * 2 + 1]), 0.f);
    *(float2*)(hres + (size_t)node * 128 + lane * 2) = o;
}

// ---------------- mean pool (batch is sorted) ------------------------------
__global__ __launch_bounds__(128) void k_pool(
    const float* __restrict__ hres, const int* __restrict__ batch,
    float* __restrict__ pooled, float* __restrict__ cnt, int n)
{
    int j = threadIdx.x;
    int n0 = blockIdx.x * 128;
    if (n0 >= n) return;
    int n1 = min(n0 + 128, n);
    int g = batch[n0];
    float acc = 0.f;
    int run = 0;
    for (int node = n0; node < n1; ++node) {
        int gb = batch[node];
        if (gb != g) {
            atomicAdd(&pooled[g * 128 + j], acc);
            if (j == 0) atomicAdd(&cnt[g], (float)run);
            acc = 0.f; run = 0; g = gb;
        }
        acc += hres[(size_t)node * 128 + j];
        run++;
    }
    atomicAdd(&pooled[g * 128 + j], acc);
    if (j == 0) atomicAdd(&cnt[g], (float)run);
}

// ---------------- FC + BN + ReLU + two heads (tiny, one block) -------------
__global__ __launch_bounds__(1024) void k_head(
    const float* __restrict__ pooled, const float* __restrict__ cnt,
    const float* __restrict__ Wfc, const float* __restrict__ bfc,
    const float* __restrict__ gamma, const float* __restrict__ beta,
    const float* __restrict__ Wheat, const float* __restrict__ bheat,
    const float* __restrict__ Wdehyd, const float* __restrict__ bdehyd,
    float* __restrict__ out)
{
    __shared__ float z[N_GRAPHS * 32];
    __shared__ float mu_s[32], rstd_s[32];
    int t = threadIdx.x;
    for (int idx = t; idx < N_GRAPHS * 32; idx += 1024) {
        int g = idx >> 5, j = idx & 31;
        float c = cnt[g];
        c = c < 1.f ? 1.f : c;
        float s = 0.f;
        for (int k = 0; k < 128; ++k)
            s = fmaf(pooled[g * 128 + k], Wfc[k * 32 + j], s);
        z[idx] = s / c + bfc[j];
    }
    __syncthreads();
    if (t < 32) {
        float mu = 0.f;
        for (int g = 0; g < N_GRAPHS; ++g) mu += z[g * 32 + t];
        mu *= (1.f / N_GRAPHS);
        float var = 0.f;
        for (int g = 0; g < N_GRAPHS; ++g) {
            float d = z[g * 32 + t] - mu;
            var = fmaf(d, d, var);
        }
        var *= (1.f / N_GRAPHS);
        mu_s[t] = mu;
        rstd_s[t] = 1.f / sqrtf(var + 1e-5f);
    }
    __syncthreads();
    for (int idx = t; idx < N_GRAPHS * 32; idx += 1024) {
        int j = idx & 31;
        float v = gamma[j] * (z[idx] - mu_s[j]) * rstd_s[j] + beta[j];
        z[idx] = v > 0.f ? v : 0.f;
    }
    __syncthreads();
    if (t < N_GRAPHS * 3) {
        int g = t / 3, r = t - g * 3;
        float s = 0.f;
        for (int j2 = 0; j2 < 32; ++j2)
            s = fmaf(z[g * 32 + j2], Wheat[j2 * 3 + r], s);
        out[t] = s + bheat[r];
    } else if (t < N_GRAPHS * 3 + N_GRAPHS * 2) {
        int idx = t - N_GRAPHS * 3;
        int g = idx >> 1, r = idx & 1;
        float s = 0.f;
        for (int j2 = 0; j2 < 32; ++j2)
            s = fmaf(z[g * 32 + j2], Wdehyd[j2 * 2 + r], s);
        out[N_GRAPHS * 3 + idx] = s + bdehyd[r];
    }
}

// ---------------- launch ---------------------------------------------------
extern "C" void kernel_launch(void* const* d_in, const int* in_sizes, int n_in,
                              void* d_out, int out_size, void* d_ws, size_t ws_size,
                              hipStream_t stream)
{
    const float* x      = (const float*)d_in[0];
    const int*   ei     = (const int*)d_in[1];
    const int*   batch  = (const int*)d_in[2];
    const float* W1     = (const float*)d_in[3];
    const float* as1w   = (const float*)d_in[4];
    const float* ad1w   = (const float*)d_in[5];
    const float* b1     = (const float*)d_in[6];
    const float* W2     = (const float*)d_in[7];
    const float* as2w   = (const float*)d_in[8];
    const float* ad2w   = (const float*)d_in[9];
    const float* b2     = (const float*)d_in[10];
    const float* Wfc    = (const float*)d_in[11];
    const float* bfc    = (const float*)d_in[12];
    const float* gamma  = (const float*)d_in[13];
    const float* beta   = (const float*)d_in[14];
    const float* Wheat  = (const float*)d_in[15];
    const float* bheat  = (const float*)d_in[16];
    const float* Wdehyd = (const float*)d_in[17];
    const float* bdehyd = (const float*)d_in[18];
    float* out = (float*)d_out;

    const int N = N_NODES;
    const int E0 = in_sizes[1] / 2;
    const int Et = E0 + N;
    const int G = N_GRAPHS;

    char* w = (char*)d_ws;
    auto alloc = [&](size_t bytes) -> char* {
        char* p = w;
        w += (bytes + 255) & ~(size_t)255;
        return p;
    };
    float* x1    = (float*)alloc((size_t)N * 512 * 4);
    float* h2    = (float*)alloc((size_t)N * 128 * 4);
    float* hres  = (float*)alloc((size_t)N * 128 * 4);
    float* a_s1  = (float*)alloc((size_t)N * 8 * 4);
    float* a_d1  = (float*)alloc((size_t)N * 8 * 4);
    float* a_s2  = (float*)alloc((size_t)N * 4 * 4);
    float* a_d2  = (float*)alloc((size_t)N * 4 * 4);
    int* deg     = (int*)alloc((size_t)(N + 1) * 4);
    int* rowstart= (int*)alloc((size_t)(N + 1) * 4);
    int* cursor  = (int*)alloc((size_t)N * 4);
    int* csr     = (int*)alloc((size_t)Et * 4);
    float* pooled= (float*)alloc((size_t)G * 128 * 4);
    float* cntf  = (float*)alloc((size_t)G * 4);

    hipMemsetAsync(deg, 0, (size_t)(N + 1) * 4, stream);
    hipMemsetAsync(pooled, 0, (size_t)G * 128 * 4, stream);
    hipMemsetAsync(cntf, 0, (size_t)G * 4, stream);

    k_att1<<<(N + 255) / 256, 256, 0, stream>>>(x, W1, as1w, ad1w, a_s1, a_d1, N);
    k_deg<<<(Et + 255) / 256, 256, 0, stream>>>(ei, deg, E0, N);
    k_scan<<<1, 1024, 0, stream>>>(deg, rowstart, cursor, N);
    k_fill<<<(Et + 255) / 256, 256, 0, stream>>>(ei, cursor, csr, E0, N);
    k_gat1<<<(N + 3) / 4, 256, 0, stream>>>(x, W1, a_s1, a_d1, rowstart, csr, b1, x1, N);
    k_gemm2<<<(N + BM2 - 1) / BM2, 256, 0, stream>>>(x1, W2, as2w, ad2w, h2, a_s2, a_d2, N);
    k_gat2<<<(N + 3) / 4, 256, 0, stream>>>(h2, a_s2, a_d2, rowstart, csr, b2, x1, hres, N);
    k_pool<<<(N + 127) / 128, 128, 0, stream>>>(hres, batch, pooled, cntf, N);
    k_head<<<1, 1024, 0, stream>>>(pooled, cntf, Wfc, bfc, gamma, beta,
                                   Wheat, bheat, Wdehyd, bdehyd, out);
}

// Round 7
// 427.129 us; speedup vs baseline: 1.0271x; 1.0271x over previous
//
#include <hip/hip_runtime.h>
#include <math.h>

// PhysioGAT pipeline on MI355X.
// Layer-1 trick: h1 = x@W1 is linear in 3-dim x, so the alpha-weighted
// neighbor sum is (sum alpha*x[src]) @ W1 — h1 is never materialized.
// Output: concat(heat[64,3], dehyd[64,2]) = 320 f32.

#define N_NODES 30000
#define N_GRAPHS 64

// ---------------- Layer-1 attention logits: a_s1/a_d1[n,8] -----------------
// a_s[n,h] = x[n,:] . P_s[:,h],  P_s[d,h] = sum_c W1[d,h*64+c]*att_src[h,c]
__global__ __launch_bounds__(256) void k_att1(
    const float* __restrict__ x, const float* __restrict__ W1,
    const float* __restrict__ asw, const float* __restrict__ adw,
    float* __restrict__ a_s, float* __restrict__ a_d, int n)
{
    __shared__ float Ps[24], Pd[24];          // idx = d*8 + h
    int t = threadIdx.x;
    if (t < 48) {
        int which = t / 24;                   // 0 -> Ps, 1 -> Pd
        int idx = t - which * 24;
        int d = idx >> 3, h = idx & 7;
        const float* av = (which ? adw : asw) + h * 64;
        const float* wr = W1 + d * 512 + h * 64;
        float s = 0.f;
        #pragma unroll 8
        for (int c = 0; c < 64; ++c) s = fmaf(wr[c], av[c], s);
        (which ? Pd : Ps)[idx] = s;
    }
    __syncthreads();
    int node = blockIdx.x * 256 + t;
    if (node >= n) return;
    float x0 = x[node * 3 + 0];
    float x1v = x[node * 3 + 1];
    float x2v = x[node * 3 + 2];
    #pragma unroll
    for (int h = 0; h < 8; ++h) {
        a_s[node * 8 + h] = fmaf(x0, Ps[h], fmaf(x1v, Ps[8 + h], x2v * Ps[16 + h]));
        a_d[node * 8 + h] = fmaf(x0, Pd[h], fmaf(x1v, Pd[8 + h], x2v * Pd[16 + h]));
    }
}

// ---------------- CSR build ------------------------------------------------
__global__ void k_deg(const int* __restrict__ ei, int* __restrict__ deg,
                      int E0, int n)
{
    int e = blockIdx.x * blockDim.x + threadIdx.x;
    int Et = E0 + n;
    if (e >= Et) return;
    int dst = (e < E0) ? ei[E0 + e] : (e - E0);
    atomicAdd(&deg[dst], 1);
}

__global__ __launch_bounds__(1024) void k_scan(
    const int* __restrict__ deg, int* __restrict__ rowstart,
    int* __restrict__ cursor, int n)
{
    __shared__ int wsum[16];
    __shared__ int woff[17];
    __shared__ int carry_s;
    int tid = threadIdx.x, lane = tid & 63, wid = tid >> 6;
    if (tid == 0) carry_s = 0;
    __syncthreads();
    int nchunks = (n + 1023) >> 10;
    for (int c = 0; c < nchunks; ++c) {
        int i = (c << 10) + tid;
        int v = (i < n) ? deg[i] : 0;
        int s = v;                                   // wave inclusive scan
        #pragma unroll
        for (int off = 1; off < 64; off <<= 1) {
            int t = __shfl_up(s, off);
            if (lane >= off) s += t;
        }
        if (lane == 63) wsum[wid] = s;
        __syncthreads();
        if (wid == 0) {                              // scan the 16 wave sums
            int ws = (lane < 16) ? wsum[lane] : 0;
            #pragma unroll
            for (int off = 1; off < 16; off <<= 1) {
                int t = __shfl_up(ws, off);
                if (lane >= off) ws += t;
            }
            if (lane < 16) woff[lane + 1] = ws;
            if (lane == 0) woff[0] = 0;
        }
        __syncthreads();
        int excl = carry_s + woff[wid] + s - v;
        if (i < n) { rowstart[i] = excl; cursor[i] = excl; }
        __syncthreads();
        if (tid == 0) carry_s += woff[16];
        __syncthreads();
    }
    if (tid == 0) rowstart[n] = carry_s;
}

__global__ void k_fill(const int* __restrict__ ei, int* __restrict__ cursor,
                       int* __restrict__ csr, int E0, int n)
{
    int e = blockIdx.x * blockDim.x + threadIdx.x;
    int Et = E0 + n;
    if (e >= Et) return;
    int src, dst;
    if (e < E0) { src = ei[e]; dst = ei[E0 + e]; }
    else        { src = e - E0; dst = e - E0; }
    int pos = atomicAdd(&cursor[dst], 1);
    csr[pos] = src;
}

// ---------------- GAT layer 1: online softmax over S = sum alpha*x[src] ----
// wave per node; hd = lane>>3 (8 heads), slot = lane&7 strides edges.
// Epilogue: x1[node, hd*64 + c] = relu(S . W1[:, col] / ssum + bias).
__global__ __launch_bounds__(256) void k_gat1(
    const float* __restrict__ x, const float* __restrict__ W1,
    const float* __restrict__ a_s, const float* __restrict__ a_d,
    const int* __restrict__ rowstart, const int* __restrict__ csr,
    const float* __restrict__ bias, float* __restrict__ x1, int n)
{
    int lane = threadIdx.x & 63;
    int node = blockIdx.x * 4 + (threadIdx.x >> 6);
    if (node >= n) return;
    int rs = rowstart[node], re = rowstart[node + 1];
    int hd = lane >> 3;
    int slot = lane & 7;
    float adn = a_d[node * 8 + hd];

    float m = -1e30f, ssum = 0.f, S0 = 0.f, S1 = 0.f, S2 = 0.f;
    for (int i = rs + slot; i < re; i += 8) {
        int src = csr[i];
        float e = a_s[src * 8 + hd] + adn;
        e = (e >= 0.f) ? e : 0.2f * e;
        float x0 = x[src * 3 + 0];
        float x1v = x[src * 3 + 1];
        float x2v = x[src * 3 + 2];
        float mn = fmaxf(m, e);
        float sc = __expf(m - mn);
        float wgt = __expf(e - mn);
        ssum = fmaf(ssum, sc, wgt);
        S0 = fmaf(S0, sc, wgt * x0);
        S1 = fmaf(S1, sc, wgt * x1v);
        S2 = fmaf(S2, sc, wgt * x2v);
        m = mn;
    }
    #pragma unroll
    for (int off = 1; off < 8; off <<= 1) {   // merge 8 slots of this head
        float mo = __shfl_xor(m, off);
        float so = __shfl_xor(ssum, off);
        float t0 = __shfl_xor(S0, off);
        float t1 = __shfl_xor(S1, off);
        float t2 = __shfl_xor(S2, off);
        float mn = fmaxf(m, mo);
        float scA = __expf(m - mn);
        float scB = __expf(mo - mn);
        ssum = ssum * scA + so * scB;
        S0 = S0 * scA + t0 * scB;
        S1 = S1 * scA + t1 * scB;
        S2 = S2 * scA + t2 * scB;
        m = mn;
    }
    float inv = 1.f / ssum;
    S0 *= inv; S1 *= inv; S2 *= inv;

    // epilogue: features j = lane*8 .. lane*8+7 (all in head hd)
    const float4* w0p = (const float4*)(W1 + lane * 8);
    const float4* w1p = (const float4*)(W1 + 512 + lane * 8);
    const float4* w2p = (const float4*)(W1 + 1024 + lane * 8);
    const float4* bp  = (const float4*)(bias + lane * 8);
    float4* xp = (float4*)(x1 + (size_t)node * 512 + lane * 8);
    #pragma unroll
    for (int q = 0; q < 2; ++q) {
        float4 w0 = w0p[q], w1 = w1p[q], w2 = w2p[q], b = bp[q];
        float4 o;
        o.x = fmaxf(fmaf(S0, w0.x, fmaf(S1, w1.x, fmaf(S2, w2.x, b.x))), 0.f);
        o.y = fmaxf(fmaf(S0, w0.y, fmaf(S1, w1.y, fmaf(S2, w2.y, b.y))), 0.f);
        o.z = fmaxf(fmaf(S0, w0.z, fmaf(S1, w1.z, fmaf(S2, w2.z, b.z))), 0.f);
        o.w = fmaxf(fmaf(S0, w0.w, fmaf(S1, w1.w, fmaf(S2, w2.w, b.w))), 0.f);
        xp[q] = o;
    }
}

// ---------------- Layer-2 GEMM + fused attention dots ----------------------
// h2[30000,128] = x1[30000,512] @ W2[512,128]; also a_s2/a_d2[n,4].
// Classic double-buffered LDS tiling: BM=64, BN=128, BK=32, 256 threads,
// 4x8 register tile. A stored transposed As[kk][row] (pad 68) so compute
// reads are float4 + 16-lane broadcast. One barrier per K-step.
#define GM_BM 64
#define GM_BK 32
#define GM_APAD 68
__global__ __launch_bounds__(256) void k_gemm2(
    const float* __restrict__ x1, const float* __restrict__ W2,
    const float* __restrict__ asw, const float* __restrict__ adw,
    float* __restrict__ h2, float* __restrict__ a_s2, float* __restrict__ a_d2,
    int n)
{
    __shared__ float As[2][GM_BK][GM_APAD];   // [kk][row] (A transposed)
    __shared__ float Bs[2][GM_BK][128];       // [kk][col]
    int tid = threadIdx.x;
    int tr = tid >> 4;                 // 0..15 -> rows tr*4..+3
    int tc = tid & 15;                 // 0..15 -> cols tc*8..+7
    int bm = blockIdx.x * GM_BM;

    // staging assignments (A: 2 float4/thread, B: 4 float4/thread)
    int aRow0 = tid >> 3;              // li = tid: row, c4
    int aC40  = tid & 7;
    int aRow1 = (tid + 256) >> 3;
    int aC41  = (tid + 256) & 7;
    float4 aReg0, aReg1, bReg[4];

    int arowg0 = bm + aRow0; arowg0 = arowg0 < n ? arowg0 : (n - 1);
    int arowg1 = bm + aRow1; arowg1 = arowg1 < n ? arowg1 : (n - 1);
    const float* aPtr0 = x1 + (size_t)arowg0 * 512 + aC40 * 4;
    const float* aPtr1 = x1 + (size_t)arowg1 * 512 + aC41 * 4;

    float acc[4][8];
    #pragma unroll
    for (int r = 0; r < 4; ++r)
        #pragma unroll
        for (int c = 0; c < 8; ++c) acc[r][c] = 0.f;

    // prologue: load + store K-step 0
    {
        aReg0 = *(const float4*)(aPtr0);
        aReg1 = *(const float4*)(aPtr1);
        #pragma unroll
        for (int j = 0; j < 4; ++j) {
            int li = tid + j * 256;
            bReg[j] = *(const float4*)(W2 + (size_t)(li >> 5) * 128 + (li & 31) * 4);
        }
        As[0][aC40 * 4 + 0][aRow0] = aReg0.x;
        As[0][aC40 * 4 + 1][aRow0] = aReg0.y;
        As[0][aC40 * 4 + 2][aRow0] = aReg0.z;
        As[0][aC40 * 4 + 3][aRow0] = aReg0.w;
        As[0][aC41 * 4 + 0][aRow1] = aReg1.x;
        As[0][aC41 * 4 + 1][aRow1] = aReg1.y;
        As[0][aC41 * 4 + 2][aRow1] = aReg1.z;
        As[0][aC41 * 4 + 3][aRow1] = aReg1.w;
        #pragma unroll
        for (int j = 0; j < 4; ++j) {
            int li = tid + j * 256;
            *(float4*)(&Bs[0][li >> 5][(li & 31) * 4]) = bReg[j];
        }
    }
    __syncthreads();

    for (int s = 0; s < 16; ++s) {
        int buf = s & 1;
        if (s < 15) {                         // issue next-step global loads
            int k0 = (s + 1) * GM_BK;
            aReg0 = *(const float4*)(aPtr0 + k0);
            aReg1 = *(const float4*)(aPtr1 + k0);
            #pragma unroll
            for (int j = 0; j < 4; ++j) {
                int li = tid + j * 256;
                bReg[j] = *(const float4*)(W2 + (size_t)(k0 + (li >> 5)) * 128 + (li & 31) * 4);
            }
        }
        #pragma unroll
        for (int kk = 0; kk < GM_BK; ++kk) {
            float4 a4 = *(const float4*)(&As[buf][kk][tr * 4]);
            float4 b0 = *(const float4*)(&Bs[buf][kk][tc * 8]);
            float4 b1 = *(const float4*)(&Bs[buf][kk][tc * 8 + 4]);
            acc[0][0] = fmaf(a4.x, b0.x, acc[0][0]);
            acc[0][1] = fmaf(a4.x, b0.y, acc[0][1]);
            acc[0][2] = fmaf(a4.x, b0.z, acc[0][2]);
            acc[0][3] = fmaf(a4.x, b0.w, acc[0][3]);
            acc[0][4] = fmaf(a4.x, b1.x, acc[0][4]);
            acc[0][5] = fmaf(a4.x, b1.y, acc[0][5]);
            acc[0][6] = fmaf(a4.x, b1.z, acc[0][6]);
            acc[0][7] = fmaf(a4.x, b1.w, acc[0][7]);
            acc[1][0] = fmaf(a4.y, b0.x, acc[1][0]);
            acc[1][1] = fmaf(a4.y, b0.y, acc[1][1]);
            acc[1][2] = fmaf(a4.y, b0.z, acc[1][2]);
            acc[1][3] = fmaf(a4.y, b0.w, acc[1][3]);
            acc[1][4] = fmaf(a4.y, b1.x, acc[1][4]);
            acc[1][5] = fmaf(a4.y, b1.y, acc[1][5]);
            acc[1][6] = fmaf(a4.y, b1.z, acc[1][6]);
            acc[1][7] = fmaf(a4.y, b1.w, acc[1][7]);
            acc[2][0] = fmaf(a4.z, b0.x, acc[2][0]);
            acc[2][1] = fmaf(a4.z, b0.y, acc[2][1]);
            acc[2][2] = fmaf(a4.z, b0.z, acc[2][2]);
            acc[2][3] = fmaf(a4.z, b0.w, acc[2][3]);
            acc[2][4] = fmaf(a4.z, b1.x, acc[2][4]);
            acc[2][5] = fmaf(a4.z, b1.y, acc[2][5]);
            acc[2][6] = fmaf(a4.z, b1.z, acc[2][6]);
            acc[2][7] = fmaf(a4.z, b1.w, acc[2][7]);
            acc[3][0] = fmaf(a4.w, b0.x, acc[3][0]);
            acc[3][1] = fmaf(a4.w, b0.y, acc[3][1]);
            acc[3][2] = fmaf(a4.w, b0.z, acc[3][2]);
            acc[3][3] = fmaf(a4.w, b0.w, acc[3][3]);
            acc[3][4] = fmaf(a4.w, b1.x, acc[3][4]);
            acc[3][5] = fmaf(a4.w, b1.y, acc[3][5]);
            acc[3][6] = fmaf(a4.w, b1.z, acc[3][6]);
            acc[3][7] = fmaf(a4.w, b1.w, acc[3][7]);
        }
        if (s < 15) {                         // store next step into buf^1
            int nb = buf ^ 1;
            As[nb][aC40 * 4 + 0][aRow0] = aReg0.x;
            As[nb][aC40 * 4 + 1][aRow0] = aReg0.y;
            As[nb][aC40 * 4 + 2][aRow0] = aReg0.z;
            As[nb][aC40 * 4 + 3][aRow0] = aReg0.w;
            As[nb][aC41 * 4 + 0][aRow1] = aReg1.x;
            As[nb][aC41 * 4 + 1][aRow1] = aReg1.y;
            As[nb][aC41 * 4 + 2][aRow1] = aReg1.z;
            As[nb][aC41 * 4 + 3][aRow1] = aReg1.w;
            #pragma unroll
            for (int j = 0; j < 4; ++j) {
                int li = tid + j * 256;
                *(float4*)(&Bs[nb][li >> 5][(li & 31) * 4]) = bReg[j];
            }
            __syncthreads();
        }
    }

    // h2 writes: rows tr*4..+3, cols tc*8..+7
    #pragma unroll
    for (int r = 0; r < 4; ++r) {
        int row = bm + tr * 4 + r;
        if (row < n) {
            float4 o0, o1;
            o0.x = acc[r][0]; o0.y = acc[r][1]; o0.z = acc[r][2]; o0.w = acc[r][3];
            o1.x = acc[r][4]; o1.y = acc[r][5]; o1.z = acc[r][6]; o1.w = acc[r][7];
            *(float4*)(h2 + (size_t)row * 128 + tc * 8) = o0;
            *(float4*)(h2 + (size_t)row * 128 + tc * 8 + 4) = o1;
        }
    }

    // fused attention dots: cols tc*8..+7 all in head tc>>2; reduce over the
    // 4 lanes sharing the head (tc bits 0..1 -> shfl_xor 1,2)
    float4 ws0 = *(const float4*)(asw + tc * 8);
    float4 ws1 = *(const float4*)(asw + tc * 8 + 4);
    float4 wd0 = *(const float4*)(adw + tc * 8);
    float4 wd1 = *(const float4*)(adw + tc * 8 + 4);
    #pragma unroll
    for (int r = 0; r < 4; ++r) {
        float ps = acc[r][0] * ws0.x + acc[r][1] * ws0.y + acc[r][2] * ws0.z +
                   acc[r][3] * ws0.w + acc[r][4] * ws1.x + acc[r][5] * ws1.y +
                   acc[r][6] * ws1.z + acc[r][7] * ws1.w;
        float pd = acc[r][0] * wd0.x + acc[r][1] * wd0.y + acc[r][2] * wd0.z +
                   acc[r][3] * wd0.w + acc[r][4] * wd1.x + acc[r][5] * wd1.y +
                   acc[r][6] * wd1.z + acc[r][7] * wd1.w;
        ps += __shfl_xor(ps, 1); ps += __shfl_xor(ps, 2);
        pd += __shfl_xor(pd, 1); pd += __shfl_xor(pd, 2);
        if ((tc & 3) == 0) {
            int row = bm + tr * 4 + r;
            if (row < n) {
                int hd = tc >> 2;
                a_s2[row * 4 + hd] = ps;
                a_d2[row * 4 + hd] = pd;
            }
        }
    }
}

// ---------------- GAT layer 2: single-pass online softmax + residual -------
// Lane owns features 2*lane, 2*lane+1 (head hd=lane>>4). All lanes iterate
// all edges; (m,ssum) duplicated within a head group -> no cross-lane reduce.
__global__ __launch_bounds__(256) void k_gat2(
    const float* __restrict__ h2, const float* __restrict__ a_s,
    const float* __restrict__ a_d, const int* __restrict__ rowstart,
    const int* __restrict__ csr, const float* __restrict__ bias,
    const float* __restrict__ x1, float* __restrict__ hres, int n)
{
    int lane = threadIdx.x & 63;
    int node = blockIdx.x * 4 + (threadIdx.x >> 6);
    if (node >= n) return;
    int rs = rowstart[node], re = rowstart[node + 1];
    int hd = lane >> 4;                       // head (0..3)
    float adn = a_d[node * 4 + hd];

    float m = -1e30f, ssum = 0.f, acc0 = 0.f, acc1 = 0.f;
    int src_next = (rs < re) ? csr[rs] : 0;
    for (int i = rs; i < re; ++i) {
        int src = src_next;
        if (i + 1 < re) src_next = csr[i + 1];
        float e = a_s[src * 4 + hd] + adn;
        e = (e >= 0.f) ? e : 0.2f * e;
        float2 hv = *(const float2*)(h2 + (size_t)src * 128 + lane * 2);
        float mn = fmaxf(m, e);
        float sc = __expf(m - mn);
        float wgt = __expf(e - mn);
        ssum = fmaf(ssum, sc, wgt);
        acc0 = fmaf(acc0, sc, wgt * hv.x);
        acc1 = fmaf(acc1, sc, wgt * hv.y);
        m = mn;
    }
    float inv = 1.f / ssum;
    float2 xv = *(const float2*)(x1 + (size_t)node * 512 + lane * 2);
    float2 o;
    o.x = xv.x + fmaxf(fmaf(acc0, inv, bias[lane * 2 + 0]), 0.f);
    o.y = xv.y + fmaxf(fmaf(acc1, inv, bias[lane * 2 + 1]), 0.f);
    *(float2*)(hres + (size_t)node * 128 + lane * 2) = o;
}

// ---------------- mean pool (batch is sorted) ------------------------------
__global__ __launch_bounds__(128) void k_pool(
    const float* __restrict__ hres, const int* __restrict__ batch,
    float* __restrict__ pooled, float* __restrict__ cnt, int n)
{
    int j = threadIdx.x;
    int n0 = blockIdx.x * 128;
    if (n0 >= n) return;
    int n1 = min(n0 + 128, n);
    int g = batch[n0];
    float acc = 0.f;
    int run = 0;
    for (int node = n0; node < n1; ++node) {
        int gb = batch[node];
        if (gb != g) {
            atomicAdd(&pooled[g * 128 + j], acc);
            if (j == 0) atomicAdd(&cnt[g], (float)run);
            acc = 0.f; run = 0; g = gb;
        }
        acc += hres[(size_t)node * 128 + j];
        run++;
    }
    atomicAdd(&pooled[g * 128 + j], acc);
    if (j == 0) atomicAdd(&cnt[g], (float)run);
}

// ---------------- FC + BN + ReLU + two heads (tiny, one block) -------------
__global__ __launch_bounds__(1024) void k_head(
    const float* __restrict__ pooled, const float* __restrict__ cnt,
    const float* __restrict__ Wfc, const float* __restrict__ bfc,
    const float* __restrict__ gamma, const float* __restrict__ beta,
    const float* __restrict__ Wheat, const float* __restrict__ bheat,
    const float* __restrict__ Wdehyd, const float* __restrict__ bdehyd,
    float* __restrict__ out)
{
    __shared__ float z[N_GRAPHS * 32];
    __shared__ float mu_s[32], rstd_s[32];
    int t = threadIdx.x;
    for (int idx = t; idx < N_GRAPHS * 32; idx += 1024) {
        int g = idx >> 5, j = idx & 31;
        float c = cnt[g];
        c = c < 1.f ? 1.f : c;
        float s = 0.f;
        for (int k = 0; k < 128; ++k)
            s = fmaf(pooled[g * 128 + k], Wfc[k * 32 + j], s);
        z[idx] = s / c + bfc[j];
    }
    __syncthreads();
    if (t < 32) {
        float mu = 0.f;
        for (int g = 0; g < N_GRAPHS; ++g) mu += z[g * 32 + t];
        mu *= (1.f / N_GRAPHS);
        float var = 0.f;
        for (int g = 0; g < N_GRAPHS; ++g) {
            float d = z[g * 32 + t] - mu;
            var = fmaf(d, d, var);
        }
        var *= (1.f / N_GRAPHS);
        mu_s[t] = mu;
        rstd_s[t] = 1.f / sqrtf(var + 1e-5f);
    }
    __syncthreads();
    for (int idx = t; idx < N_GRAPHS * 32; idx += 1024) {
        int j = idx & 31;
        float v = gamma[j] * (z[idx] - mu_s[j]) * rstd_s[j] + beta[j];
        z[idx] = v > 0.f ? v : 0.f;
    }
    __syncthreads();
    if (t < N_GRAPHS * 3) {
        int g = t / 3, r = t - g * 3;
        float s = 0.f;
        for (int j2 = 0; j2 < 32; ++j2)
            s = fmaf(z[g * 32 + j2], Wheat[j2 * 3 + r], s);
        out[t] = s + bheat[r];
    } else if (t < N_GRAPHS * 3 + N_GRAPHS * 2) {
        int idx = t - N_GRAPHS * 3;
        int g = idx >> 1, r = idx & 1;
        float s = 0.f;
        for (int j2 = 0; j2 < 32; ++j2)
            s = fmaf(z[g * 32 + j2], Wdehyd[j2 * 2 + r], s);
        out[N_GRAPHS * 3 + idx] = s + bdehyd[r];
    }
}

// ---------------- launch ---------------------------------------------------
extern "C" void kernel_launch(void* const* d_in, const int* in_sizes, int n_in,
                              void* d_out, int out_size, void* d_ws, size_t ws_size,
                              hipStream_t stream)
{
    const float* x      = (const float*)d_in[0];
    const int*   ei     = (const int*)d_in[1];
    const int*   batch  = (const int*)d_in[2];
    const float* W1     = (const float*)d_in[3];
    const float* as1w   = (const float*)d_in[4];
    const float* ad1w   = (const float*)d_in[5];
    const float* b1     = (const float*)d_in[6];
    const float* W2     = (const float*)d_in[7];
    const float* as2w   = (const float*)d_in[8];
    const float* ad2w   = (const float*)d_in[9];
    const float* b2     = (const float*)d_in[10];
    const float* Wfc    = (const float*)d_in[11];
    const float* bfc    = (const float*)d_in[12];
    const float* gamma  = (const float*)d_in[13];
    const float* beta   = (const float*)d_in[14];
    const float* Wheat  = (const float*)d_in[15];
    const float* bheat  = (const float*)d_in[16];
    const float* Wdehyd = (const float*)d_in[17];
    const float* bdehyd = (const float*)d_in[18];
    float* out = (float*)d_out;

    const int N = N_NODES;
    const int E0 = in_sizes[1] / 2;
    const int Et = E0 + N;
    const int G = N_GRAPHS;

    char* w = (char*)d_ws;
    auto alloc = [&](size_t bytes) -> char* {
        char* p = w;
        w += (bytes + 255) & ~(size_t)255;
        return p;
    };
    float* x1    = (float*)alloc((size_t)N * 512 * 4);
    float* h2    = (float*)alloc((size_t)N * 128 * 4);
    float* hres  = (float*)alloc((size_t)N * 128 * 4);
    float* a_s1  = (float*)alloc((size_t)N * 8 * 4);
    float* a_d1  = (float*)alloc((size_t)N * 8 * 4);
    float* a_s2  = (float*)alloc((size_t)N * 4 * 4);
    float* a_d2  = (float*)alloc((size_t)N * 4 * 4);
    int* deg     = (int*)alloc((size_t)(N + 1) * 4);
    int* rowstart= (int*)alloc((size_t)(N + 1) * 4);
    int* cursor  = (int*)alloc((size_t)N * 4);
    int* csr     = (int*)alloc((size_t)Et * 4);
    float* pooled= (float*)alloc((size_t)G * 128 * 4);
    float* cntf  = (float*)alloc((size_t)G * 4);

    hipMemsetAsync(deg, 0, (size_t)(N + 1) * 4, stream);
    hipMemsetAsync(pooled, 0, (size_t)G * 128 * 4, stream);
    hipMemsetAsync(cntf, 0, (size_t)G * 4, stream);

    k_att1<<<(N + 255) / 256, 256, 0, stream>>>(x, W1, as1w, ad1w, a_s1, a_d1, N);
    k_deg<<<(Et + 255) / 256, 256, 0, stream>>>(ei, deg, E0, N);
    k_scan<<<1, 1024, 0, stream>>>(deg, rowstart, cursor, N);
    k_fill<<<(Et + 255) / 256, 256, 0, stream>>>(ei, cursor, csr, E0, N);
    k_gat1<<<(N + 3) / 4, 256, 0, stream>>>(x, W1, a_s1, a_d1, rowstart, csr, b1, x1, N);
    k_gemm2<<<(N + GM_BM - 1) / GM_BM, 256, 0, stream>>>(x1, W2, as2w, ad2w, h2, a_s2, a_d2, N);
    k_gat2<<<(N + 3) / 4, 256, 0, stream>>>(h2, a_s2, a_d2, rowstart, csr, b2, x1, hres, N);
    k_pool<<<(N + 127) / 128, 128, 0, stream>>>(hres, batch, pooled, cntf, N);
    k_head<<<1, 1024, 0, stream>>>(pooled, cntf, Wfc, bfc, gamma, beta,
                                   Wheat, bheat, Wdehyd, bdehyd, out);
}

// Round 8
// 419.095 us; speedup vs baseline: 1.0468x; 1.0192x over previous
//
#include <hip/hip_runtime.h>
#include <math.h>

// PhysioGAT pipeline on MI355X.
// Layer-1 trick: h1 = x@W1 is linear in 3-dim x, so the alpha-weighted
// neighbor sum is (sum alpha*x[src]) @ W1. We store only the normalized
// 3-vector Shat[n][8] (3.8 MB) — x1 [30000,512] (61 MB) NEVER exists.
// The layer-2 GEMM generates its A-tile on the fly from Shat (+W1,b1),
// all L1/L2-hot; the residual is recomputed from Shat in k_gat2.
// Output: concat(heat[64,3], dehyd[64,2]) = 320 f32.

#define N_NODES 30000
#define N_GRAPHS 64

// ---------------- Layer-1 attention logits: a_s1/a_d1[n,8] -----------------
__global__ __launch_bounds__(256) void k_att1(
    const float* __restrict__ x, const float* __restrict__ W1,
    const float* __restrict__ asw, const float* __restrict__ adw,
    float* __restrict__ a_s, float* __restrict__ a_d, int n)
{
    __shared__ float Ps[24], Pd[24];          // idx = d*8 + h
    int t = threadIdx.x;
    if (t < 48) {
        int which = t / 24;                   // 0 -> Ps, 1 -> Pd
        int idx = t - which * 24;
        int d = idx >> 3, h = idx & 7;
        const float* av = (which ? adw : asw) + h * 64;
        const float* wr = W1 + d * 512 + h * 64;
        float s = 0.f;
        #pragma unroll 8
        for (int c = 0; c < 64; ++c) s = fmaf(wr[c], av[c], s);
        (which ? Pd : Ps)[idx] = s;
    }
    __syncthreads();
    int node = blockIdx.x * 256 + t;
    if (node >= n) return;
    float x0 = x[node * 3 + 0];
    float x1v = x[node * 3 + 1];
    float x2v = x[node * 3 + 2];
    #pragma unroll
    for (int h = 0; h < 8; ++h) {
        a_s[node * 8 + h] = fmaf(x0, Ps[h], fmaf(x1v, Ps[8 + h], x2v * Ps[16 + h]));
        a_d[node * 8 + h] = fmaf(x0, Pd[h], fmaf(x1v, Pd[8 + h], x2v * Pd[16 + h]));
    }
}

// ---------------- CSR build ------------------------------------------------
__global__ void k_deg(const int* __restrict__ ei, int* __restrict__ deg,
                      int E0, int n)
{
    int e = blockIdx.x * blockDim.x + threadIdx.x;
    int Et = E0 + n;
    if (e >= Et) return;
    int dst = (e < E0) ? ei[E0 + e] : (e - E0);
    atomicAdd(&deg[dst], 1);
}

__global__ __launch_bounds__(1024) void k_scan(
    const int* __restrict__ deg, int* __restrict__ rowstart,
    int* __restrict__ cursor, int n)
{
    __shared__ int wsum[16];
    __shared__ int woff[17];
    __shared__ int carry_s;
    int tid = threadIdx.x, lane = tid & 63, wid = tid >> 6;
    if (tid == 0) carry_s = 0;
    __syncthreads();
    int nchunks = (n + 1023) >> 10;
    for (int c = 0; c < nchunks; ++c) {
        int i = (c << 10) + tid;
        int v = (i < n) ? deg[i] : 0;
        int s = v;                                   // wave inclusive scan
        #pragma unroll
        for (int off = 1; off < 64; off <<= 1) {
            int t = __shfl_up(s, off);
            if (lane >= off) s += t;
        }
        if (lane == 63) wsum[wid] = s;
        __syncthreads();
        if (wid == 0) {                              // scan the 16 wave sums
            int ws = (lane < 16) ? wsum[lane] : 0;
            #pragma unroll
            for (int off = 1; off < 16; off <<= 1) {
                int t = __shfl_up(ws, off);
                if (lane >= off) ws += t;
            }
            if (lane < 16) woff[lane + 1] = ws;
            if (lane == 0) woff[0] = 0;
        }
        __syncthreads();
        int excl = carry_s + woff[wid] + s - v;
        if (i < n) { rowstart[i] = excl; cursor[i] = excl; }
        __syncthreads();
        if (tid == 0) carry_s += woff[16];
        __syncthreads();
    }
    if (tid == 0) rowstart[n] = carry_s;
}

__global__ void k_fill(const int* __restrict__ ei, int* __restrict__ cursor,
                       int* __restrict__ csr, int E0, int n)
{
    int e = blockIdx.x * blockDim.x + threadIdx.x;
    int Et = E0 + n;
    if (e >= Et) return;
    int src, dst;
    if (e < E0) { src = ei[e]; dst = ei[E0 + e]; }
    else        { src = e - E0; dst = e - E0; }
    int pos = atomicAdd(&cursor[dst], 1);
    csr[pos] = src;
}

// ---------------- GAT layer 1: online softmax -> Shat[n][8][4] -------------
// wave per node; hd = lane>>3 (8 heads), slot = lane&7 strides edges.
// Shat[node][hd] = (sum alpha*x[src]) / ssum  (3 floats + pad).
__global__ __launch_bounds__(256) void k_gat1(
    const float* __restrict__ x, const float* __restrict__ a_s,
    const float* __restrict__ a_d, const int* __restrict__ rowstart,
    const int* __restrict__ csr, float* __restrict__ Shat, int n)
{
    int lane = threadIdx.x & 63;
    int node = blockIdx.x * 4 + (threadIdx.x >> 6);
    if (node >= n) return;
    int rs = rowstart[node], re = rowstart[node + 1];
    int hd = lane >> 3;
    int slot = lane & 7;
    float adn = a_d[node * 8 + hd];

    float m = -1e30f, ssum = 0.f, S0 = 0.f, S1 = 0.f, S2 = 0.f;
    for (int i = rs + slot; i < re; i += 8) {
        int src = csr[i];
        float e = a_s[src * 8 + hd] + adn;
        e = (e >= 0.f) ? e : 0.2f * e;
        float x0 = x[src * 3 + 0];
        float x1v = x[src * 3 + 1];
        float x2v = x[src * 3 + 2];
        float mn = fmaxf(m, e);
        float sc = __expf(m - mn);
        float wgt = __expf(e - mn);
        ssum = fmaf(ssum, sc, wgt);
        S0 = fmaf(S0, sc, wgt * x0);
        S1 = fmaf(S1, sc, wgt * x1v);
        S2 = fmaf(S2, sc, wgt * x2v);
        m = mn;
    }
    #pragma unroll
    for (int off = 1; off < 8; off <<= 1) {   // merge 8 slots of this head
        float mo = __shfl_xor(m, off);
        float so = __shfl_xor(ssum, off);
        float t0 = __shfl_xor(S0, off);
        float t1 = __shfl_xor(S1, off);
        float t2 = __shfl_xor(S2, off);
        float mn = fmaxf(m, mo);
        float scA = __expf(m - mn);
        float scB = __expf(mo - mn);
        ssum = ssum * scA + so * scB;
        S0 = S0 * scA + t0 * scB;
        S1 = S1 * scA + t1 * scB;
        S2 = S2 * scA + t2 * scB;
        m = mn;
    }
    if (slot == 0) {
        float inv = 1.f / ssum;
        float4 o;
        o.x = S0 * inv; o.y = S1 * inv; o.z = S2 * inv; o.w = 0.f;
        *(float4*)(Shat + ((size_t)node * 8 + hd) * 4) = o;
    }
}

// ---------------- Layer-2 GEMM (A generated from Shat) + fused att dots ----
// h2[30000,128] = relu(Shat@W1+b1) @ W2. BM=64, BK=32, 256 threads, 4x8.
// A-tile generated INTO LDS from Shat (8 KB/block) + W1/b1 (L1-hot):
// no large-matrix A traffic at all. Bank-conflict-free layouts:
// As writes row=lane (2-way), Bs reads at {tc*4, 64+tc*4} (2-way).
#define GM_BM 64
#define GM_BK 32
#define GM_APAD 68
__global__ __launch_bounds__(256) void k_gemm2(
    const float* __restrict__ Shat, const float* __restrict__ W1,
    const float* __restrict__ bias1, const float* __restrict__ W2,
    const float* __restrict__ asw, const float* __restrict__ adw,
    float* __restrict__ h2, float* __restrict__ a_s2, float* __restrict__ a_d2,
    int n)
{
    __shared__ float As[2][GM_BK][GM_APAD];   // [kk][row]
    __shared__ float Bs[2][GM_BK][128];       // [kk][col]
    int tid = threadIdx.x;
    int tr = tid >> 4;                 // rows tr*4..+3
    int tc = tid & 15;                 // cols tc*4..+3 and 64+tc*4..+3
    int bm = blockIdx.x * GM_BM;

    // A staging: thread generates row sRow, kk in [sKq, sKq+8)
    int sRow = tid & 63;
    int sKq  = (tid >> 6) << 3;        // wave-uniform
    int srowg = bm + sRow; if (srowg >= n) srowg = n - 1;
    const float* shp = Shat + (size_t)srowg * 32;   // [8][4]

    float acc[4][8];
    #pragma unroll
    for (int r = 0; r < 4; ++r)
        #pragma unroll
        for (int c = 0; c < 8; ++c) acc[r][c] = 0.f;

    float4 sh, wA0, wA1, wB0, wB1, wC0, wC1, bb0, bb1, bReg[4];

    auto loadStage = [&](int s) {
        int k0 = s * GM_BK;
        sh  = *(const float4*)(shp + ((k0 >> 6) << 2));
        const float* wk = W1 + k0 + sKq;
        wA0 = *(const float4*)(wk);         wA1 = *(const float4*)(wk + 4);
        wB0 = *(const float4*)(wk + 512);   wB1 = *(const float4*)(wk + 516);
        wC0 = *(const float4*)(wk + 1024);  wC1 = *(const float4*)(wk + 1028);
        bb0 = *(const float4*)(bias1 + k0 + sKq);
        bb1 = *(const float4*)(bias1 + k0 + sKq + 4);
        #pragma unroll
        for (int j = 0; j < 4; ++j) {
            int li = tid + j * 256;
            bReg[j] = *(const float4*)(W2 + (size_t)(k0 + (li >> 5)) * 128 + (li & 31) * 4);
        }
    };
    auto storeStage = [&](int b) {
        float va[8];
        va[0] = fmaf(sh.x, wA0.x, fmaf(sh.y, wB0.x, fmaf(sh.z, wC0.x, bb0.x)));
        va[1] = fmaf(sh.x, wA0.y, fmaf(sh.y, wB0.y, fmaf(sh.z, wC0.y, bb0.y)));
        va[2] = fmaf(sh.x, wA0.z, fmaf(sh.y, wB0.z, fmaf(sh.z, wC0.z, bb0.z)));
        va[3] = fmaf(sh.x, wA0.w, fmaf(sh.y, wB0.w, fmaf(sh.z, wC0.w, bb0.w)));
        va[4] = fmaf(sh.x, wA1.x, fmaf(sh.y, wB1.x, fmaf(sh.z, wC1.x, bb1.x)));
        va[5] = fmaf(sh.x, wA1.y, fmaf(sh.y, wB1.y, fmaf(sh.z, wC1.y, bb1.y)));
        va[6] = fmaf(sh.x, wA1.z, fmaf(sh.y, wB1.z, fmaf(sh.z, wC1.z, bb1.z)));
        va[7] = fmaf(sh.x, wA1.w, fmaf(sh.y, wB1.w, fmaf(sh.z, wC1.w, bb1.w)));
        #pragma unroll
        for (int j = 0; j < 8; ++j)
            As[b][sKq + j][sRow] = fmaxf(va[j], 0.f);
        #pragma unroll
        for (int j = 0; j < 4; ++j) {
            int li = tid + j * 256;
            *(float4*)(&Bs[b][li >> 5][(li & 31) * 4]) = bReg[j];
        }
    };

    loadStage(0);
    storeStage(0);
    __syncthreads();

    for (int s = 0; s < 16; ++s) {
        int buf = s & 1;
        if (s < 15) loadStage(s + 1);
        #pragma unroll
        for (int kk = 0; kk < GM_BK; ++kk) {
            float4 a4  = *(const float4*)(&As[buf][kk][tr * 4]);
            float4 b0  = *(const float4*)(&Bs[buf][kk][tc * 4]);
            float4 b1v = *(const float4*)(&Bs[buf][kk][64 + tc * 4]);
            acc[0][0] = fmaf(a4.x, b0.x, acc[0][0]);
            acc[0][1] = fmaf(a4.x, b0.y, acc[0][1]);
            acc[0][2] = fmaf(a4.x, b0.z, acc[0][2]);
            acc[0][3] = fmaf(a4.x, b0.w, acc[0][3]);
            acc[0][4] = fmaf(a4.x, b1v.x, acc[0][4]);
            acc[0][5] = fmaf(a4.x, b1v.y, acc[0][5]);
            acc[0][6] = fmaf(a4.x, b1v.z, acc[0][6]);
            acc[0][7] = fmaf(a4.x, b1v.w, acc[0][7]);
            acc[1][0] = fmaf(a4.y, b0.x, acc[1][0]);
            acc[1][1] = fmaf(a4.y, b0.y, acc[1][1]);
            acc[1][2] = fmaf(a4.y, b0.z, acc[1][2]);
            acc[1][3] = fmaf(a4.y, b0.w, acc[1][3]);
            acc[1][4] = fmaf(a4.y, b1v.x, acc[1][4]);
            acc[1][5] = fmaf(a4.y, b1v.y, acc[1][5]);
            acc[1][6] = fmaf(a4.y, b1v.z, acc[1][6]);
            acc[1][7] = fmaf(a4.y, b1v.w, acc[1][7]);
            acc[2][0] = fmaf(a4.z, b0.x, acc[2][0]);
            acc[2][1] = fmaf(a4.z, b0.y, acc[2][1]);
            acc[2][2] = fmaf(a4.z, b0.z, acc[2][2]);
            acc[2][3] = fmaf(a4.z, b0.w, acc[2][3]);
            acc[2][4] = fmaf(a4.z, b1v.x, acc[2][4]);
            acc[2][5] = fmaf(a4.z, b1v.y, acc[2][5]);
            acc[2][6] = fmaf(a4.z, b1v.z, acc[2][6]);
            acc[2][7] = fmaf(a4.z, b1v.w, acc[2][7]);
            acc[3][0] = fmaf(a4.w, b0.x, acc[3][0]);
            acc[3][1] = fmaf(a4.w, b0.y, acc[3][1]);
            acc[3][2] = fmaf(a4.w, b0.z, acc[3][2]);
            acc[3][3] = fmaf(a4.w, b0.w, acc[3][3]);
            acc[3][4] = fmaf(a4.w, b1v.x, acc[3][4]);
            acc[3][5] = fmaf(a4.w, b1v.y, acc[3][5]);
            acc[3][6] = fmaf(a4.w, b1v.z, acc[3][6]);
            acc[3][7] = fmaf(a4.w, b1v.w, acc[3][7]);
        }
        if (s < 15) {
            storeStage(buf ^ 1);
            __syncthreads();
        }
    }

    // h2 writes: rows tr*4..+3, cols {tc*4..+3, 64+tc*4..+3}
    #pragma unroll
    for (int r = 0; r < 4; ++r) {
        int row = bm + tr * 4 + r;
        if (row < n) {
            float4 oL, oH;
            oL.x = acc[r][0]; oL.y = acc[r][1]; oL.z = acc[r][2]; oL.w = acc[r][3];
            oH.x = acc[r][4]; oH.y = acc[r][5]; oH.z = acc[r][6]; oH.w = acc[r][7];
            *(float4*)(h2 + (size_t)row * 128 + tc * 4) = oL;
            *(float4*)(h2 + (size_t)row * 128 + 64 + tc * 4) = oH;
        }
    }

    // fused attention dots. Low cols head = tc>>3 (0/1); high head = 2+(tc>>3).
    // Reduce over the 8 lanes sharing a head (tc bits 0..2).
    float4 wsL = *(const float4*)(asw + tc * 4);
    float4 wsH = *(const float4*)(asw + 64 + tc * 4);
    float4 wdL = *(const float4*)(adw + tc * 4);
    float4 wdH = *(const float4*)(adw + 64 + tc * 4);
    #pragma unroll
    for (int r = 0; r < 4; ++r) {
        float psL = acc[r][0] * wsL.x + acc[r][1] * wsL.y + acc[r][2] * wsL.z + acc[r][3] * wsL.w;
        float pdL = acc[r][0] * wdL.x + acc[r][1] * wdL.y + acc[r][2] * wdL.z + acc[r][3] * wdL.w;
        float psH = acc[r][4] * wsH.x + acc[r][5] * wsH.y + acc[r][6] * wsH.z + acc[r][7] * wsH.w;
        float pdH = acc[r][4] * wdH.x + acc[r][5] * wdH.y + acc[r][6] * wdH.z + acc[r][7] * wdH.w;
        #pragma unroll
        for (int off = 1; off < 8; off <<= 1) {
            psL += __shfl_xor(psL, off);
            pdL += __shfl_xor(pdL, off);
            psH += __shfl_xor(psH, off);
            pdH += __shfl_xor(pdH, off);
        }
        if ((tc & 7) == 0) {
            int row = bm + tr * 4 + r;
            if (row < n) {
                int h0 = tc >> 3;                  // 0 or 1
                a_s2[row * 4 + h0] = psL;
                a_d2[row * 4 + h0] = pdL;
                a_s2[row * 4 + 2 + h0] = psH;
                a_d2[row * 4 + 2 + h0] = pdH;
            }
        }
    }
}

// ---------------- GAT layer 2: online softmax + residual from Shat ---------
// Lane owns features 2*lane, 2*lane+1 (att head hd=lane>>4; layer-1 head
// for the residual hh=lane>>5). Residual recomputed from Shat (x1 gone).
__global__ __launch_bounds__(256) void k_gat2(
    const float* __restrict__ h2, const float* __restrict__ a_s,
    const float* __restrict__ a_d, const int* __restrict__ rowstart,
    const int* __restrict__ csr, const float* __restrict__ bias,
    const float* __restrict__ Shat, const float* __restrict__ W1,
    const float* __restrict__ bias1, float* __restrict__ hres, int n)
{
    int lane = threadIdx.x & 63;
    int node = blockIdx.x * 4 + (threadIdx.x >> 6);
    if (node >= n) return;
    int rs = rowstart[node], re = rowstart[node + 1];
    int hd = lane >> 4;                       // layer-2 head (0..3)
    float adn = a_d[node * 4 + hd];

    float m = -1e30f, ssum = 0.f, acc0 = 0.f, acc1 = 0.f;
    int src_next = (rs < re) ? csr[rs] : 0;
    for (int i = rs; i < re; ++i) {
        int src = src_next;
        if (i + 1 < re) src_next = csr[i + 1];
        float e = a_s[src * 4 + hd] + adn;
        e = (e >= 0.f) ? e : 0.2f * e;
        float2 hv = *(const float2*)(h2 + (size_t)src * 128 + lane * 2);
        float mn = fmaxf(m, e);
        float sc = __expf(m - mn);
        float wgt = __expf(e - mn);
        ssum = fmaf(ssum, sc, wgt);
        acc0 = fmaf(acc0, sc, wgt * hv.x);
        acc1 = fmaf(acc1, sc, wgt * hv.y);
        m = mn;
    }
    float inv = 1.f / ssum;

    // residual x1[node, 2*lane .. 2*lane+1] recomputed from Shat
    int hh = lane >> 5;                       // layer-1 head of these cols
    float4 shv = *(const float4*)(Shat + ((size_t)node * 8 + hh) * 4);
    float2 w0 = *(const float2*)(W1 + lane * 2);
    float2 w1v = *(const float2*)(W1 + 512 + lane * 2);
    float2 w2v = *(const float2*)(W1 + 1024 + lane * 2);
    float2 bv = *(const float2*)(bias1 + lane * 2);
    float r0 = fmaxf(fmaf(shv.x, w0.x, fmaf(shv.y, w1v.x, fmaf(shv.z, w2v.x, bv.x))), 0.f);
    float r1 = fmaxf(fmaf(shv.x, w0.y, fmaf(shv.y, w1v.y, fmaf(shv.z, w2v.y, bv.y))), 0.f);

    float2 o;
    o.x = r0 + fmaxf(fmaf(acc0, inv, bias[lane * 2 + 0]), 0.f);
    o.y = r1 + fmaxf(fmaf(acc1, inv, bias[lane * 2 + 1]), 0.f);
    *(float2*)(hres + (size_t)node * 128 + lane * 2) = o;
}

// ---------------- mean pool (batch is sorted) ------------------------------
__global__ __launch_bounds__(128) void k_pool(
    const float* __restrict__ hres, const int* __restrict__ batch,
    float* __restrict__ pooled, float* __restrict__ cnt, int n)
{
    int j = threadIdx.x;
    int n0 = blockIdx.x * 128;
    if (n0 >= n) return;
    int n1 = min(n0 + 128, n);
    int g = batch[n0];
    float acc = 0.f;
    int run = 0;
    for (int node = n0; node < n1; ++node) {
        int gb = batch[node];
        if (gb != g) {
            atomicAdd(&pooled[g * 128 + j], acc);
            if (j == 0) atomicAdd(&cnt[g], (float)run);
            acc = 0.f; run = 0; g = gb;
        }
        acc += hres[(size_t)node * 128 + j];
        run++;
    }
    atomicAdd(&pooled[g * 128 + j], acc);
    if (j == 0) atomicAdd(&cnt[g], (float)run);
}

// ---------------- FC + BN + ReLU + two heads (tiny, one block) -------------
__global__ __launch_bounds__(1024) void k_head(
    const float* __restrict__ pooled, const float* __restrict__ cnt,
    const float* __restrict__ Wfc, const float* __restrict__ bfc,
    const float* __restrict__ gamma, const float* __restrict__ beta,
    const float* __restrict__ Wheat, const float* __restrict__ bheat,
    const float* __restrict__ Wdehyd, const float* __restrict__ bdehyd,
    float* __restrict__ out)
{
    __shared__ float z[N_GRAPHS * 32];
    __shared__ float mu_s[32], rstd_s[32];
    int t = threadIdx.x;
    for (int idx = t; idx < N_GRAPHS * 32; idx += 1024) {
        int g = idx >> 5, j = idx & 31;
        float c = cnt[g];
        c = c < 1.f ? 1.f : c;
        float s = 0.f;
        for (int k = 0; k < 128; ++k)
            s = fmaf(pooled[g * 128 + k], Wfc[k * 32 + j], s);
        z[idx] = s / c + bfc[j];
    }
    __syncthreads();
    if (t < 32) {
        float mu = 0.f;
        for (int g = 0; g < N_GRAPHS; ++g) mu += z[g * 32 + t];
        mu *= (1.f / N_GRAPHS);
        float var = 0.f;
        for (int g = 0; g < N_GRAPHS; ++g) {
            float d = z[g * 32 + t] - mu;
            var = fmaf(d, d, var);
        }
        var *= (1.f / N_GRAPHS);
        mu_s[t] = mu;
        rstd_s[t] = 1.f / sqrtf(var + 1e-5f);
    }
    __syncthreads();
    for (int idx = t; idx < N_GRAPHS * 32; idx += 1024) {
        int j = idx & 31;
        float v = gamma[j] * (z[idx] - mu_s[j]) * rstd_s[j] + beta[j];
        z[idx] = v > 0.f ? v : 0.f;
    }
    __syncthreads();
    if (t < N_GRAPHS * 3) {
        int g = t / 3, r = t - g * 3;
        float s = 0.f;
        for (int j2 = 0; j2 < 32; ++j2)
            s = fmaf(z[g * 32 + j2], Wheat[j2 * 3 + r], s);
        out[t] = s + bheat[r];
    } else if (t < N_GRAPHS * 3 + N_GRAPHS * 2) {
        int idx = t - N_GRAPHS * 3;
        int g = idx >> 1, r = idx & 1;
        float s = 0.f;
        for (int j2 = 0; j2 < 32; ++j2)
            s = fmaf(z[g * 32 + j2], Wdehyd[j2 * 2 + r], s);
        out[N_GRAPHS * 3 + idx] = s + bdehyd[r];
    }
}

// ---------------- launch ---------------------------------------------------
extern "C" void kernel_launch(void* const* d_in, const int* in_sizes, int n_in,
                              void* d_out, int out_size, void* d_ws, size_t ws_size,
                              hipStream_t stream)
{
    const float* x      = (const float*)d_in[0];
    const int*   ei     = (const int*)d_in[1];
    const int*   batch  = (const int*)d_in[2];
    const float* W1     = (const float*)d_in[3];
    const float* as1w   = (const float*)d_in[4];
    const float* ad1w   = (const float*)d_in[5];
    const float* b1     = (const float*)d_in[6];
    const float* W2     = (const float*)d_in[7];
    const float* as2w   = (const float*)d_in[8];
    const float* ad2w   = (const float*)d_in[9];
    const float* b2     = (const float*)d_in[10];
    const float* Wfc    = (const float*)d_in[11];
    const float* bfc    = (const float*)d_in[12];
    const float* gamma  = (const float*)d_in[13];
    const float* beta   = (const float*)d_in[14];
    const float* Wheat  = (const float*)d_in[15];
    const float* bheat  = (const float*)d_in[16];
    const float* Wdehyd = (const float*)d_in[17];
    const float* bdehyd = (const float*)d_in[18];
    float* out = (float*)d_out;

    const int N = N_NODES;
    const int E0 = in_sizes[1] / 2;
    const int Et = E0 + N;
    const int G = N_GRAPHS;

    char* w = (char*)d_ws;
    auto alloc = [&](size_t bytes) -> char* {
        char* p = w;
        w += (bytes + 255) & ~(size_t)255;
        return p;
    };
    float* Shat  = (float*)alloc((size_t)N * 32 * 4);   // [N][8][4]
    float* h2    = (float*)alloc((size_t)N * 128 * 4);
    float* hres  = (float*)alloc((size_t)N * 128 * 4);
    float* a_s1  = (float*)alloc((size_t)N * 8 * 4);
    float* a_d1  = (float*)alloc((size_t)N * 8 * 4);
    float* a_s2  = (float*)alloc((size_t)N * 4 * 4);
    float* a_d2  = (float*)alloc((size_t)N * 4 * 4);
    int* deg     = (int*)alloc((size_t)(N + 1) * 4);
    int* rowstart= (int*)alloc((size_t)(N + 1) * 4);
    int* cursor  = (int*)alloc((size_t)N * 4);
    int* csr     = (int*)alloc((size_t)Et * 4);
    float* pooled= (float*)alloc((size_t)G * 128 * 4);
    float* cntf  = (float*)alloc((size_t)G * 4);

    hipMemsetAsync(deg, 0, (size_t)(N + 1) * 4, stream);
    hipMemsetAsync(pooled, 0, (size_t)G * 128 * 4, stream);
    hipMemsetAsync(cntf, 0, (size_t)G * 4, stream);

    k_att1<<<(N + 255) / 256, 256, 0, stream>>>(x, W1, as1w, ad1w, a_s1, a_d1, N);
    k_deg<<<(Et + 255) / 256, 256, 0, stream>>>(ei, deg, E0, N);
    k_scan<<<1, 1024, 0, stream>>>(deg, rowstart, cursor, N);
    k_fill<<<(Et + 255) / 256, 256, 0, stream>>>(ei, cursor, csr, E0, N);
    k_gat1<<<(N + 3) / 4, 256, 0, stream>>>(x, a_s1, a_d1, rowstart, csr, Shat, N);
    k_gemm2<<<(N + GM_BM - 1) / GM_BM, 256, 0, stream>>>(Shat, W1, b1, W2, as2w, ad2w, h2, a_s2, a_d2, N);
    k_gat2<<<(N + 3) / 4, 256, 0, stream>>>(h2, a_s2, a_d2, rowstart, csr, b2, Shat, W1, b1, hres, N);
    k_pool<<<(N + 127) / 128, 128, 0, stream>>>(hres, batch, pooled, cntf, N);
    k_head<<<1, 1024, 0, stream>>>(pooled, cntf, Wfc, bfc, gamma, beta,
                                   Wheat, bheat, Wdehyd, bdehyd, out);
}

// Round 9
// 415.376 us; speedup vs baseline: 1.0562x; 1.0090x over previous
//
#include <hip/hip_runtime.h>
#include <math.h>

// PhysioGAT pipeline on MI355X.
// Layer-1 trick: h1 = x@W1 is linear in 3-dim x, so the alpha-weighted
// neighbor sum is (sum alpha*x[src]) @ W1. We store only the normalized
// 3-vector Shat[n][8] (3.8 MB) — x1 [30000,512] (61 MB) NEVER exists.
// The layer-2 GEMM generates its A-tile on the fly from Shat (+W1,b1),
// all L1/L2-hot; the residual is recomputed from Shat in k_gat2.
// Output: concat(heat[64,3], dehyd[64,2]) = 320 f32.

#define N_NODES 30000
#define N_GRAPHS 64

// ---------------- Layer-1 attention logits: a_s1/a_d1[n,8] -----------------
__global__ __launch_bounds__(256) void k_att1(
    const float* __restrict__ x, const float* __restrict__ W1,
    const float* __restrict__ asw, const float* __restrict__ adw,
    float* __restrict__ a_s, float* __restrict__ a_d, int n)
{
    __shared__ float Ps[24], Pd[24];          // idx = d*8 + h
    int t = threadIdx.x;
    if (t < 48) {
        int which = t / 24;                   // 0 -> Ps, 1 -> Pd
        int idx = t - which * 24;
        int d = idx >> 3, h = idx & 7;
        const float* av = (which ? adw : asw) + h * 64;
        const float* wr = W1 + d * 512 + h * 64;
        float s = 0.f;
        #pragma unroll 8
        for (int c = 0; c < 64; ++c) s = fmaf(wr[c], av[c], s);
        (which ? Pd : Ps)[idx] = s;
    }
    __syncthreads();
    int node = blockIdx.x * 256 + t;
    if (node >= n) return;
    float x0 = x[node * 3 + 0];
    float x1v = x[node * 3 + 1];
    float x2v = x[node * 3 + 2];
    #pragma unroll
    for (int h = 0; h < 8; ++h) {
        a_s[node * 8 + h] = fmaf(x0, Ps[h], fmaf(x1v, Ps[8 + h], x2v * Ps[16 + h]));
        a_d[node * 8 + h] = fmaf(x0, Pd[h], fmaf(x1v, Pd[8 + h], x2v * Pd[16 + h]));
    }
}

// ---------------- CSR build ------------------------------------------------
__global__ void k_deg(const int* __restrict__ ei, int* __restrict__ deg,
                      int E0, int n)
{
    int e = blockIdx.x * blockDim.x + threadIdx.x;
    int Et = E0 + n;
    if (e >= Et) return;
    int dst = (e < E0) ? ei[E0 + e] : (e - E0);
    atomicAdd(&deg[dst], 1);
}

__global__ __launch_bounds__(1024) void k_scan(
    const int* __restrict__ deg, int* __restrict__ rowstart,
    int* __restrict__ cursor, int n)
{
    __shared__ int wsum[16];
    __shared__ int woff[17];
    __shared__ int carry_s;
    int tid = threadIdx.x, lane = tid & 63, wid = tid >> 6;
    if (tid == 0) carry_s = 0;
    __syncthreads();
    int nchunks = (n + 1023) >> 10;
    for (int c = 0; c < nchunks; ++c) {
        int i = (c << 10) + tid;
        int v = (i < n) ? deg[i] : 0;
        int s = v;                                   // wave inclusive scan
        #pragma unroll
        for (int off = 1; off < 64; off <<= 1) {
            int t = __shfl_up(s, off);
            if (lane >= off) s += t;
        }
        if (lane == 63) wsum[wid] = s;
        __syncthreads();
        if (wid == 0) {                              // scan the 16 wave sums
            int ws = (lane < 16) ? wsum[lane] : 0;
            #pragma unroll
            for (int off = 1; off < 16; off <<= 1) {
                int t = __shfl_up(ws, off);
                if (lane >= off) ws += t;
            }
            if (lane < 16) woff[lane + 1] = ws;
            if (lane == 0) woff[0] = 0;
        }
        __syncthreads();
        int excl = carry_s + woff[wid] + s - v;
        if (i < n) { rowstart[i] = excl; cursor[i] = excl; }
        __syncthreads();
        if (tid == 0) carry_s += woff[16];
        __syncthreads();
    }
    if (tid == 0) rowstart[n] = carry_s;
}

__global__ void k_fill(const int* __restrict__ ei, int* __restrict__ cursor,
                       int* __restrict__ csr, int E0, int n)
{
    int e = blockIdx.x * blockDim.x + threadIdx.x;
    int Et = E0 + n;
    if (e >= Et) return;
    int src, dst;
    if (e < E0) { src = ei[e]; dst = ei[E0 + e]; }
    else        { src = e - E0; dst = e - E0; }
    int pos = atomicAdd(&cursor[dst], 1);
    csr[pos] = src;
}

// ---------------- GAT layer 1: online softmax -> Shat[n][8][4] -------------
__global__ __launch_bounds__(256) void k_gat1(
    const float* __restrict__ x, const float* __restrict__ a_s,
    const float* __restrict__ a_d, const int* __restrict__ rowstart,
    const int* __restrict__ csr, float* __restrict__ Shat, int n)
{
    int lane = threadIdx.x & 63;
    int node = blockIdx.x * 4 + (threadIdx.x >> 6);
    if (node >= n) return;
    int rs = rowstart[node], re = rowstart[node + 1];
    int hd = lane >> 3;
    int slot = lane & 7;
    float adn = a_d[node * 8 + hd];

    float m = -1e30f, ssum = 0.f, S0 = 0.f, S1 = 0.f, S2 = 0.f;
    for (int i = rs + slot; i < re; i += 8) {
        int src = csr[i];
        float e = a_s[src * 8 + hd] + adn;
        e = (e >= 0.f) ? e : 0.2f * e;
        float x0 = x[src * 3 + 0];
        float x1v = x[src * 3 + 1];
        float x2v = x[src * 3 + 2];
        float mn = fmaxf(m, e);
        float sc = __expf(m - mn);
        float wgt = __expf(e - mn);
        ssum = fmaf(ssum, sc, wgt);
        S0 = fmaf(S0, sc, wgt * x0);
        S1 = fmaf(S1, sc, wgt * x1v);
        S2 = fmaf(S2, sc, wgt * x2v);
        m = mn;
    }
    #pragma unroll
    for (int off = 1; off < 8; off <<= 1) {   // merge 8 slots of this head
        float mo = __shfl_xor(m, off);
        float so = __shfl_xor(ssum, off);
        float t0 = __shfl_xor(S0, off);
        float t1 = __shfl_xor(S1, off);
        float t2 = __shfl_xor(S2, off);
        float mn = fmaxf(m, mo);
        float scA = __expf(m - mn);
        float scB = __expf(mo - mn);
        ssum = ssum * scA + so * scB;
        S0 = S0 * scA + t0 * scB;
        S1 = S1 * scA + t1 * scB;
        S2 = S2 * scA + t2 * scB;
        m = mn;
    }
    if (slot == 0) {
        float inv = 1.f / ssum;
        float4 o;
        o.x = S0 * inv; o.y = S1 * inv; o.z = S2 * inv; o.w = 0.f;
        *(float4*)(Shat + ((size_t)node * 8 + hd) * 4) = o;
    }
}

// ---------------- Layer-2 GEMM (A generated from Shat) + fused att dots ----
// h2[30000,128] = relu(Shat@W1+b1) @ W2.
// BM=32, BK=32, 256 threads, 4x4 register tile, SINGLE-buffered LDS (21 KB).
// 938 blocks (3.7/CU) + low VGPR -> occupancy; latency hidden by TLP.
#define GM_BM 32
#define GM_BK 32
#define GM_APAD 36
__global__ __launch_bounds__(256) void k_gemm2(
    const float* __restrict__ Shat, const float* __restrict__ W1,
    const float* __restrict__ bias1, const float* __restrict__ W2,
    const float* __restrict__ asw, const float* __restrict__ adw,
    float* __restrict__ h2, float* __restrict__ a_s2, float* __restrict__ a_d2,
    int n)
{
    __shared__ float As[GM_BK][GM_APAD];   // [kk][row]
    __shared__ float Bs[GM_BK][128];       // [kk][col]
    int tid = threadIdx.x;
    int tr = tid >> 5;                 // 0..7 -> rows tr*4..+3
    int tc = tid & 31;                 // cols tc*4..+3
    int bm = blockIdx.x * GM_BM;

    // A staging: thread generates row sRow, kk in [sK4, sK4+4)
    int sRow = tid & 31;
    int sK4  = (tid >> 5) << 2;        // 0,4,..,28 (wave-uniform-ish)
    int srowg = bm + sRow; if (srowg >= n) srowg = n - 1;
    const float* shp = Shat + (size_t)srowg * 32;   // [8][4]

    float acc[4][4];
    #pragma unroll
    for (int r = 0; r < 4; ++r)
        #pragma unroll
        for (int c = 0; c < 4; ++c) acc[r][c] = 0.f;

    for (int s = 0; s < 16; ++s) {
        int k0 = s * GM_BK;
        // ---- stage A (generated) ----
        {
            int kg = k0 + sK4;                       // 4-span, single head
            float4 sh = *(const float4*)(shp + ((kg >> 6) << 2));
            float4 w0 = *(const float4*)(W1 + kg);
            float4 w1v = *(const float4*)(W1 + 512 + kg);
            float4 w2v = *(const float4*)(W1 + 1024 + kg);
            float4 bb = *(const float4*)(bias1 + kg);
            As[sK4 + 0][sRow] = fmaxf(fmaf(sh.x, w0.x, fmaf(sh.y, w1v.x, fmaf(sh.z, w2v.x, bb.x))), 0.f);
            As[sK4 + 1][sRow] = fmaxf(fmaf(sh.x, w0.y, fmaf(sh.y, w1v.y, fmaf(sh.z, w2v.y, bb.y))), 0.f);
            As[sK4 + 2][sRow] = fmaxf(fmaf(sh.x, w0.z, fmaf(sh.y, w1v.z, fmaf(sh.z, w2v.z, bb.z))), 0.f);
            As[sK4 + 3][sRow] = fmaxf(fmaf(sh.x, w0.w, fmaf(sh.y, w1v.w, fmaf(sh.z, w2v.w, bb.w))), 0.f);
        }
        // ---- stage B ----
        #pragma unroll
        for (int j = 0; j < 4; ++j) {
            int li = tid + j * 256;
            *(float4*)(&Bs[li >> 5][(li & 31) * 4]) =
                *(const float4*)(W2 + (size_t)(k0 + (li >> 5)) * 128 + (li & 31) * 4);
        }
        __syncthreads();
        // ---- compute ----
        #pragma unroll
        for (int kk = 0; kk < GM_BK; ++kk) {
            float4 a4 = *(const float4*)(&As[kk][tr * 4]);
            float4 b4 = *(const float4*)(&Bs[kk][tc * 4]);
            acc[0][0] = fmaf(a4.x, b4.x, acc[0][0]);
            acc[0][1] = fmaf(a4.x, b4.y, acc[0][1]);
            acc[0][2] = fmaf(a4.x, b4.z, acc[0][2]);
            acc[0][3] = fmaf(a4.x, b4.w, acc[0][3]);
            acc[1][0] = fmaf(a4.y, b4.x, acc[1][0]);
            acc[1][1] = fmaf(a4.y, b4.y, acc[1][1]);
            acc[1][2] = fmaf(a4.y, b4.z, acc[1][2]);
            acc[1][3] = fmaf(a4.y, b4.w, acc[1][3]);
            acc[2][0] = fmaf(a4.z, b4.x, acc[2][0]);
            acc[2][1] = fmaf(a4.z, b4.y, acc[2][1]);
            acc[2][2] = fmaf(a4.z, b4.z, acc[2][2]);
            acc[2][3] = fmaf(a4.z, b4.w, acc[2][3]);
            acc[3][0] = fmaf(a4.w, b4.x, acc[3][0]);
            acc[3][1] = fmaf(a4.w, b4.y, acc[3][1]);
            acc[3][2] = fmaf(a4.w, b4.z, acc[3][2]);
            acc[3][3] = fmaf(a4.w, b4.w, acc[3][3]);
        }
        if (s < 15) __syncthreads();
    }

    // h2 writes: rows tr*4..+3, cols tc*4..+3
    #pragma unroll
    for (int r = 0; r < 4; ++r) {
        int row = bm + tr * 4 + r;
        if (row < n) {
            float4 o;
            o.x = acc[r][0]; o.y = acc[r][1]; o.z = acc[r][2]; o.w = acc[r][3];
            *(float4*)(h2 + (size_t)row * 128 + tc * 4) = o;
        }
    }

    // fused attention dots: cols tc*4..+3 all in head tc>>3.
    // Reduce over the 8 lanes sharing a head (tc bits 0..2 -> xor 1,2,4).
    float4 ws = *(const float4*)(asw + tc * 4);
    float4 wd = *(const float4*)(adw + tc * 4);
    #pragma unroll
    for (int r = 0; r < 4; ++r) {
        float ps = acc[r][0] * ws.x + acc[r][1] * ws.y + acc[r][2] * ws.z + acc[r][3] * ws.w;
        float pd = acc[r][0] * wd.x + acc[r][1] * wd.y + acc[r][2] * wd.z + acc[r][3] * wd.w;
        ps += __shfl_xor(ps, 1); ps += __shfl_xor(ps, 2); ps += __shfl_xor(ps, 4);
        pd += __shfl_xor(pd, 1); pd += __shfl_xor(pd, 2); pd += __shfl_xor(pd, 4);
        if ((tc & 7) == 0) {
            int row = bm + tr * 4 + r;
            if (row < n) {
                int hd = tc >> 3;
                a_s2[row * 4 + hd] = ps;
                a_d2[row * 4 + hd] = pd;
            }
        }
    }
}

// ---------------- GAT layer 2: online softmax + residual from Shat ---------
__global__ __launch_bounds__(256) void k_gat2(
    const float* __restrict__ h2, const float* __restrict__ a_s,
    const float* __restrict__ a_d, const int* __restrict__ rowstart,
    const int* __restrict__ csr, const float* __restrict__ bias,
    const float* __restrict__ Shat, const float* __restrict__ W1,
    const float* __restrict__ bias1, float* __restrict__ hres, int n)
{
    int lane = threadIdx.x & 63;
    int node = blockIdx.x * 4 + (threadIdx.x >> 6);
    if (node >= n) return;
    int rs = rowstart[node], re = rowstart[node + 1];
    int hd = lane >> 4;                       // layer-2 head (0..3)
    float adn = a_d[node * 4 + hd];

    float m = -1e30f, ssum = 0.f, acc0 = 0.f, acc1 = 0.f;
    int src_next = (rs < re) ? csr[rs] : 0;
    for (int i = rs; i < re; ++i) {
        int src = src_next;
        if (i + 1 < re) src_next = csr[i + 1];
        float e = a_s[src * 4 + hd] + adn;
        e = (e >= 0.f) ? e : 0.2f * e;
        float2 hv = *(const float2*)(h2 + (size_t)src * 128 + lane * 2);
        float mn = fmaxf(m, e);
        float sc = __expf(m - mn);
        float wgt = __expf(e - mn);
        ssum = fmaf(ssum, sc, wgt);
        acc0 = fmaf(acc0, sc, wgt * hv.x);
        acc1 = fmaf(acc1, sc, wgt * hv.y);
        m = mn;
    }
    float inv = 1.f / ssum;

    // residual x1[node, 2*lane .. 2*lane+1] recomputed from Shat
    int hh = lane >> 5;                       // layer-1 head of these cols
    float4 shv = *(const float4*)(Shat + ((size_t)node * 8 + hh) * 4);
    float2 w0 = *(const float2*)(W1 + lane * 2);
    float2 w1v = *(const float2*)(W1 + 512 + lane * 2);
    float2 w2v = *(const float2*)(W1 + 1024 + lane * 2);
    float2 bv = *(const float2*)(bias1 + lane * 2);
    float r0 = fmaxf(fmaf(shv.x, w0.x, fmaf(shv.y, w1v.x, fmaf(shv.z, w2v.x, bv.x))), 0.f);
    float r1 = fmaxf(fmaf(shv.x, w0.y, fmaf(shv.y, w1v.y, fmaf(shv.z, w2v.y, bv.y))), 0.f);

    float2 o;
    o.x = r0 + fmaxf(fmaf(acc0, inv, bias[lane * 2 + 0]), 0.f);
    o.y = r1 + fmaxf(fmaf(acc1, inv, bias[lane * 2 + 1]), 0.f);
    *(float2*)(hres + (size_t)node * 128 + lane * 2) = o;
}

// ---------------- mean pool (batch is sorted) ------------------------------
__global__ __launch_bounds__(128) void k_pool(
    const float* __restrict__ hres, const int* __restrict__ batch,
    float* __restrict__ pooled, float* __restrict__ cnt, int n)
{
    int j = threadIdx.x;
    int n0 = blockIdx.x * 128;
    if (n0 >= n) return;
    int n1 = min(n0 + 128, n);
    int g = batch[n0];
    float acc = 0.f;
    int run = 0;
    for (int node = n0; node < n1; ++node) {
        int gb = batch[node];
        if (gb != g) {
            atomicAdd(&pooled[g * 128 + j], acc);
            if (j == 0) atomicAdd(&cnt[g], (float)run);
            acc = 0.f; run = 0; g = gb;
        }
        acc += hres[(size_t)node * 128 + j];
        run++;
    }
    atomicAdd(&pooled[g * 128 + j], acc);
    if (j == 0) atomicAdd(&cnt[g], (float)run);
}

// ---------------- FC + BN + ReLU + two heads (tiny, one block) -------------
__global__ __launch_bounds__(1024) void k_head(
    const float* __restrict__ pooled, const float* __restrict__ cnt,
    const float* __restrict__ Wfc, const float* __restrict__ bfc,
    const float* __restrict__ gamma, const float* __restrict__ beta,
    const float* __restrict__ Wheat, const float* __restrict__ bheat,
    const float* __restrict__ Wdehyd, const float* __restrict__ bdehyd,
    float* __restrict__ out)
{
    __shared__ float z[N_GRAPHS * 32];
    __shared__ float mu_s[32], rstd_s[32];
    int t = threadIdx.x;
    for (int idx = t; idx < N_GRAPHS * 32; idx += 1024) {
        int g = idx >> 5, j = idx & 31;
        float c = cnt[g];
        c = c < 1.f ? 1.f : c;
        float s = 0.f;
        for (int k = 0; k < 128; ++k)
            s = fmaf(pooled[g * 128 + k], Wfc[k * 32 + j], s);
        z[idx] = s / c + bfc[j];
    }
    __syncthreads();
    if (t < 32) {
        float mu = 0.f;
        for (int g = 0; g < N_GRAPHS; ++g) mu += z[g * 32 + t];
        mu *= (1.f / N_GRAPHS);
        float var = 0.f;
        for (int g = 0; g < N_GRAPHS; ++g) {
            float d = z[g * 32 + t] - mu;
            var = fmaf(d, d, var);
        }
        var *= (1.f / N_GRAPHS);
        mu_s[t] = mu;
        rstd_s[t] = 1.f / sqrtf(var + 1e-5f);
    }
    __syncthreads();
    for (int idx = t; idx < N_GRAPHS * 32; idx += 1024) {
        int j = idx & 31;
        float v = gamma[j] * (z[idx] - mu_s[j]) * rstd_s[j] + beta[j];
        z[idx] = v > 0.f ? v : 0.f;
    }
    __syncthreads();
    if (t < N_GRAPHS * 3) {
        int g = t / 3, r = t - g * 3;
        float s = 0.f;
        for (int j2 = 0; j2 < 32; ++j2)
            s = fmaf(z[g * 32 + j2], Wheat[j2 * 3 + r], s);
        out[t] = s + bheat[r];
    } else if (t < N_GRAPHS * 3 + N_GRAPHS * 2) {
        int idx = t - N_GRAPHS * 3;
        int g = idx >> 1, r = idx & 1;
        float s = 0.f;
        for (int j2 = 0; j2 < 32; ++j2)
            s = fmaf(z[g * 32 + j2], Wdehyd[j2 * 2 + r], s);
        out[N_GRAPHS * 3 + idx] = s + bdehyd[r];
    }
}

// ---------------- launch ---------------------------------------------------
extern "C" void kernel_launch(void* const* d_in, const int* in_sizes, int n_in,
                              void* d_out, int out_size, void* d_ws, size_t ws_size,
                              hipStream_t stream)
{
    const float* x      = (const float*)d_in[0];
    const int*   ei     = (const int*)d_in[1];
    const int*   batch  = (const int*)d_in[2];
    const float* W1     = (const float*)d_in[3];
    const float* as1w   = (const float*)d_in[4];
    const float* ad1w   = (const float*)d_in[5];
    const float* b1     = (const float*)d_in[6];
    const float* W2     = (const float*)d_in[7];
    const float* as2w   = (const float*)d_in[8];
    const float* ad2w   = (const float*)d_in[9];
    const float* b2     = (const float*)d_in[10];
    const float* Wfc    = (const float*)d_in[11];
    const float* bfc    = (const float*)d_in[12];
    const float* gamma  = (const float*)d_in[13];
    const float* beta   = (const float*)d_in[14];
    const float* Wheat  = (const float*)d_in[15];
    const float* bheat  = (const float*)d_in[16];
    const float* Wdehyd = (const float*)d_in[17];
    const float* bdehyd = (const float*)d_in[18];
    float* out = (float*)d_out;

    const int N = N_NODES;
    const int E0 = in_sizes[1] / 2;
    const int Et = E0 + N;
    const int G = N_GRAPHS;

    char* w = (char*)d_ws;
    auto alloc = [&](size_t bytes) -> char* {
        char* p = w;
        w += (bytes + 255) & ~(size_t)255;
        return p;
    };
    float* Shat  = (float*)alloc((size_t)N * 32 * 4);   // [N][8][4]
    float* h2    = (float*)alloc((size_t)N * 128 * 4);
    float* hres  = (float*)alloc((size_t)N * 128 * 4);
    float* a_s1  = (float*)alloc((size_t)N * 8 * 4);
    float* a_d1  = (float*)alloc((size_t)N * 8 * 4);
    float* a_s2  = (float*)alloc((size_t)N * 4 * 4);
    float* a_d2  = (float*)alloc((size_t)N * 4 * 4);
    int* deg     = (int*)alloc((size_t)(N + 1) * 4);
    int* rowstart= (int*)alloc((size_t)(N + 1) * 4);
    int* cursor  = (int*)alloc((size_t)N * 4);
    int* csr     = (int*)alloc((size_t)Et * 4);
    float* pooled= (float*)alloc((size_t)G * 128 * 4);
    float* cntf  = (float*)alloc((size_t)G * 4);

    hipMemsetAsync(deg, 0, (size_t)(N + 1) * 4, stream);
    hipMemsetAsync(pooled, 0, (size_t)G * 128 * 4, stream);
    hipMemsetAsync(cntf, 0, (size_t)G * 4, stream);

    k_att1<<<(N + 255) / 256, 256, 0, stream>>>(x, W1, as1w, ad1w, a_s1, a_d1, N);
    k_deg<<<(Et + 255) / 256, 256, 0, stream>>>(ei, deg, E0, N);
    k_scan<<<1, 1024, 0, stream>>>(deg, rowstart, cursor, N);
    k_fill<<<(Et + 255) / 256, 256, 0, stream>>>(ei, cursor, csr, E0, N);
    k_gat1<<<(N + 3) / 4, 256, 0, stream>>>(x, a_s1, a_d1, rowstart, csr, Shat, N);
    k_gemm2<<<(N + GM_BM - 1) / GM_BM, 256, 0, stream>>>(Shat, W1, b1, W2, as2w, ad2w, h2, a_s2, a_d2, N);
    k_gat2<<<(N + 3) / 4, 256, 0, stream>>>(h2, a_s2, a_d2, rowstart, csr, b2, Shat, W1, b1, hres, N);
    k_pool<<<(N + 127) / 128, 128, 0, stream>>>(hres, batch, pooled, cntf, N);
    k_head<<<1, 1024, 0, stream>>>(pooled, cntf, Wfc, bfc, gamma, beta,
                                   Wheat, bheat, Wdehyd, bdehyd, out);
}